// Round 13
// baseline (597.136 us; speedup 1.0000x reference)
//
#include <hip/hip_runtime.h>
#include <hip/hip_bf16.h>
#include <math.h>

// N=50000, E=400000, F_IN=128, HID=64, OUT=40, H=4
#define SLOPE 0.2f

typedef unsigned short bf16_t;
typedef short bh8 __attribute__((ext_vector_type(8)));
typedef unsigned short us8 __attribute__((ext_vector_type(8)));
typedef float f32x4 __attribute__((ext_vector_type(4)));

__device__ __forceinline__ float bf2f(bf16_t x) {
    return __uint_as_float((unsigned)x << 16);
}
__device__ __forceinline__ bf16_t f2bf(float v) {
    unsigned u = __float_as_uint(v);
    return (bf16_t)((u + 0x7FFFu + ((u >> 16) & 1u)) >> 16);  // RNE
}
__device__ __forceinline__ ushort2 pk_f2bf(float a, float b) {
    __hip_bfloat162 h2 = __float22bfloat162_rn(float2{a, b});  // v_cvt_pk_bf16_f32
    union { __hip_bfloat162 h; ushort2 u; } u;
    u.h = h2;
    return u.u;
}

// ---------------- fused histogram + weight conversion (R15/R16-verified) ----------------

__global__ void hist_and_convert(
    const int* __restrict__ dst, int E, int eblocks, int* __restrict__ deg,
    const float* __restrict__ w0, const float* __restrict__ w1, const float* __restrict__ w2,
    const float* __restrict__ w3, const float* __restrict__ w4,
    const float* __restrict__ w5, const float* __restrict__ w6,
    const float* __restrict__ wr2, const float* __restrict__ br2,
    bf16_t* __restrict__ t0, bf16_t* __restrict__ t1, bf16_t* __restrict__ t2,
    bf16_t* __restrict__ t3, bf16_t* __restrict__ t4,
    bf16_t* __restrict__ t5, bf16_t* __restrict__ t6,
    bf16_t* __restrict__ teff, float* __restrict__ b_eff)
{
    int t = threadIdx.x;
    if ((int)blockIdx.x < eblocks) {
        int e = blockIdx.x * 256 + t;
        if (e < E) atomicAdd(&deg[dst[e]], 1);
        return;
    }
    int b = blockIdx.x - eblocks;
    const float* W; bf16_t* T; int K, Nc, lb;
    if (b < 384) {
        int g = b / 128; lb = b - g * 128;
        W = g == 0 ? w0 : (g == 1 ? w1 : w2);
        T = g == 0 ? t0 : (g == 1 ? t1 : t2);
        K = 128; Nc = 256;
    } else if (b < 896) {
        int g = (b - 384) / 256; lb = (b - 384) - g * 256;
        W = g == 0 ? w3 : w4; T = g == 0 ? t3 : t4;
        K = 256; Nc = 256;
    } else if (b < 1280) {
        int g = (b - 896) / 192; lb = (b - 896) - g * 192;
        W = g == 0 ? w5 : w6; T = g == 0 ? t5 : t6;
        K = 256; Nc = 160;
    } else {
        lb = b - 1280;
        int idx = lb * 256 + t;          // 64*256 = 16384 elems
        int n = idx >> 8, k = idx & 255;
        float v = 0.f;
        if (n < 40)
            v = 0.25f * (wr2[(size_t)k * 160 + n] + wr2[(size_t)k * 160 + 40 + n] +
                         wr2[(size_t)k * 160 + 80 + n] + wr2[(size_t)k * 160 + 120 + n]);
        teff[idx] = f2bf(v);
        if (lb == 0 && t < 40)
            b_eff[t] = 0.25f * (br2[t] + br2[40 + t] + br2[80 + t] + br2[120 + t]);
        return;
    }
    int idx = lb * 256 + t;
    int n = idx / K, k = idx - n * K;
    float v = (n < Nc) ? W[(size_t)k * Nc + n] : 0.f;
    T[idx] = f2bf(v);
}

// ---------------- CSR scan + degree-bucket sort ----------------
// deg_chunk_sum additionally builds a 128-bucket degree histogram (LDS-staged).

__global__ void deg_chunk_sum(const int* __restrict__ deg, int n,
                              int* __restrict__ chunk_sums, int* __restrict__ bcnt) {
    __shared__ int sm[256];
    __shared__ int hl[128];
    int t = threadIdx.x;
    if (t < 128) hl[t] = 0;
    __syncthreads();
    int base = blockIdx.x * 1024;
    int s = 0;
    for (int i = t; i < 1024; i += 256) {
        int idx = base + i;
        if (idx < n) {
            int d = deg[idx];
            s += d;
            atomicAdd(&hl[d < 127 ? d : 127], 1);
        }
    }
    sm[t] = s;
    __syncthreads();
    for (int off = 128; off > 0; off >>= 1) {
        if (t < off) sm[t] += sm[t + off];
        __syncthreads();
    }
    if (t == 0) chunk_sums[blockIdx.x] = sm[0];
    if (t < 128 && hl[t]) atomicAdd(&bcnt[t], hl[t]);
}

// scan_write: row_start prefix (as before) + degree-sorted node permutation.
// Counting sort: per-block LDS rank within bucket, one global atomic per
// bucket per block, then scatter perm[sbase[b]+gbase[b]+rank] = node.
__global__ void scan_write(const int* __restrict__ deg, int n,
                           const int* __restrict__ chunk_sums,
                           int* __restrict__ row_start, int Etot,
                           const int* __restrict__ bcnt, int* __restrict__ bfill,
                           int* __restrict__ perm) {
    __shared__ int sm[256];
    __shared__ int s_pref;
    __shared__ int sbase[128];
    __shared__ int lcnt[128];
    __shared__ int gbase[128];
    int base = blockIdx.x * 1024;
    int t = threadIdx.x;

    if (t < 128) lcnt[t] = 0;

    // wave 0: sum chunk_sums[0..blockIdx.x) via wave-reduce
    if (t < 64) {
        int v = (t < (int)blockIdx.x) ? chunk_sums[t] : 0;
#pragma unroll
        for (int off = 32; off > 0; off >>= 1)
            v += __shfl_down(v, off, 64);
        if (t == 0) s_pref = v;
    }
    // thread 128: serial exclusive prefix of the 128-bucket histogram
    if (t == 128) {
        int run = 0;
        for (int i = 0; i < 128; i++) { sbase[i] = run; run += bcnt[i]; }
    }

    int vv[4];
    int tsum = 0;
#pragma unroll
    for (int j = 0; j < 4; j++) {
        int idx = base + t * 4 + j;
        vv[j] = (idx < n) ? deg[idx] : 0;
        tsum += vv[j];
    }
    sm[t] = tsum;
    __syncthreads();
    for (int off = 1; off < 256; off <<= 1) {
        int x = (t >= off) ? sm[t - off] : 0;
        __syncthreads();
        sm[t] += x;
        __syncthreads();
    }
    int excl = sm[t] - tsum + s_pref;
#pragma unroll
    for (int j = 0; j < 4; j++) {
        int idx = base + t * 4 + j;
        if (idx < n) row_start[idx] = excl;
        excl += vv[j];
    }
    if (blockIdx.x == 0 && t == 0) row_start[n] = Etot;

    // ---- degree-bucket scatter ----
    int rnk[4], bb[4];
#pragma unroll
    for (int j = 0; j < 4; j++) {
        int idx = base + t * 4 + j;
        if (idx < n) {
            bb[j] = vv[j] < 127 ? vv[j] : 127;
            rnk[j] = atomicAdd(&lcnt[bb[j]], 1);
        } else bb[j] = -1;
    }
    __syncthreads();
    if (t < 128 && lcnt[t]) gbase[t] = atomicAdd(&bfill[t], lcnt[t]);
    __syncthreads();
#pragma unroll
    for (int j = 0; j < 4; j++) {
        int idx = base + t * 4 + j;
        if (bb[j] >= 0)
            perm[sbase[bb[j]] + gbase[bb[j]] + rnk[j]] = idx;
    }
}

// ---------------- single-A-stage multi-output MFMA GEMM (R14/R17 config) ----------------
// DO_SCATTER: blocks [mtiles, mtiles+eblocks) run the edge scatter (independent
// work overlapped with the layer-0 GEMM in one dispatch) and return early.

template <typename TA, int NOUT, int KTOT, int NPAD, bool SPLIT40, bool HAS_EFF, bool DO_SCATTER>
__global__ __launch_bounds__(256) void gemm_lds(
    const TA* __restrict__ A,
    const bf16_t* __restrict__ Wt0, const bf16_t* __restrict__ Wt1, const bf16_t* __restrict__ Wt2,
    const float* __restrict__ bias0, const float* __restrict__ bias1, const float* __restrict__ bias2,
    bf16_t* __restrict__ C0, bf16_t* __restrict__ C1, bf16_t* __restrict__ C2,
    const bf16_t* __restrict__ Wte, const float* __restrict__ biase, float* __restrict__ Ce,
    int M, int Nc,
    const int* __restrict__ e_dst, const int* __restrict__ e_src, int E,
    const int* __restrict__ row_start, int* __restrict__ fill,
    int* __restrict__ src_sorted, int mtiles)
{
    constexpr int LSTR = KTOT + 8;     // stage row stride
    constexpr int ESTR = 38;           // epilogue row stride
    constexpr int KC = KTOT / 32;
    __shared__ bf16_t As[64 * LSTR];
    __shared__ bf16_t Ep[4 * 64 * ESTR];

    int tid = threadIdx.x;

    if (DO_SCATTER && (int)blockIdx.x >= mtiles) {
        int e = (blockIdx.x - mtiles) * 256 + tid;
        if (e < E) {
            int d_ = e_dst[e];
            int pos = row_start[d_] + atomicAdd(&fill[d_], 1);
            src_sorted[pos] = e_src[e];
        }
        return;
    }

    int lane = tid & 63, w = tid >> 6;
    int lm = lane & 15, lq = lane >> 4;
    int m0 = blockIdx.x * 64;

    const bf16_t* Wts[3] = {Wt0, Wt1, Wt2};
    const float* biases[3] = {bias0, bias1, bias2};
    bf16_t* Cs[3] = {C0, C1, C2};

    // ---- stage A slab (64 rows x KTOT) once ----
    if (sizeof(TA) == 4) {            // KTOT == 128, f32 input
#pragma unroll
        for (int it = 0; it < 4; it++) {
            int idx = tid + it * 256;  // 1024 chunks of 8 floats
            int r = idx >> 4, c = idx & 15;
            int gm = m0 + r; if (gm >= M) gm = M - 1;
            const float* ap = (const float*)A + (size_t)gm * KTOT + c * 8;
            float4 lo = *(const float4*)ap;
            float4 hi = *(const float4*)(ap + 4);
            ushort2 p0 = pk_f2bf(lo.x, lo.y), p1 = pk_f2bf(lo.z, lo.w);
            ushort2 p2 = pk_f2bf(hi.x, hi.y), p3 = pk_f2bf(hi.z, hi.w);
            bh8 v = { (short)p0.x, (short)p0.y, (short)p1.x, (short)p1.y,
                      (short)p2.x, (short)p2.y, (short)p3.x, (short)p3.y };
            *(bh8*)(As + r * LSTR + c * 8) = v;
        }
    } else {                           // KTOT == 256, bf16 input
#pragma unroll
        for (int it = 0; it < 8; it++) {
            int idx = tid + it * 256;  // 2048 chunks of 8 bf16
            int r = idx >> 5, c = idx & 31;
            int gm = m0 + r; if (gm >= M) gm = M - 1;
            bh8 v = *(const bh8*)((const bf16_t*)A + (size_t)gm * KTOT + c * 8);
            *(bh8*)(As + r * LSTR + c * 8) = v;
        }
    }
    __syncthreads();   // the ONLY barrier

    bf16_t* ep = Ep + w * (64 * ESTR);
    constexpr int NCHUNK = (NPAD + 127) / 128;

#pragma unroll
    for (int chunk = 0; chunk < NCHUNK; chunk++) {
        int n0 = chunk * 128 + w * 32;
        if (n0 >= NPAD) continue;      // no barriers inside -> safe

        int boff[NOUT][2];
#pragma unroll
        for (int o = 0; o < NOUT; o++)
#pragma unroll
            for (int nt = 0; nt < 2; nt++)
                boff[o][nt] = (n0 + nt * 16 + lm) * KTOT + lq * 8;

        f32x4 acc[NOUT][4][2];
#pragma unroll
        for (int o = 0; o < NOUT; o++)
#pragma unroll
            for (int i = 0; i < 4; i++)
#pragma unroll
                for (int j = 0; j < 2; j++)
                    acc[o][i][j] = (f32x4){0.f, 0.f, 0.f, 0.f};

        bh8 bf_cur[NOUT][2], bf_nxt[NOUT][2];
#pragma unroll
        for (int o = 0; o < NOUT; o++)
#pragma unroll
            for (int nt = 0; nt < 2; nt++)
                bf_cur[o][nt] = *(const bh8*)(Wts[o] + boff[o][nt]);

#pragma unroll
        for (int kc = 0; kc < KC; kc++) {
            if (kc + 1 < KC) {
#pragma unroll
                for (int o = 0; o < NOUT; o++)
#pragma unroll
                    for (int nt = 0; nt < 2; nt++)
                        bf_nxt[o][nt] = *(const bh8*)(Wts[o] + boff[o][nt] + (kc + 1) * 32);
            }
            bh8 af[4];
#pragma unroll
            for (int mt = 0; mt < 4; mt++)
                af[mt] = *(const bh8*)(As + (mt * 16 + lm) * LSTR + kc * 32 + lq * 8);
#pragma unroll
            for (int o = 0; o < NOUT; o++)
#pragma unroll
                for (int mt = 0; mt < 4; mt++)
#pragma unroll
                    for (int nt = 0; nt < 2; nt++)
                        acc[o][mt][nt] = __builtin_amdgcn_mfma_f32_16x16x32_bf16(af[mt], bf_cur[o][nt], acc[o][mt][nt], 0, 0, 0);
            if (kc + 1 < KC) {
#pragma unroll
                for (int o = 0; o < NOUT; o++)
#pragma unroll
                    for (int nt = 0; nt < 2; nt++)
                        bf_cur[o][nt] = bf_nxt[o][nt];
            }
        }

        // ---- per-wave epilogue: private LDS tile -> full-line global stores ----
#pragma unroll
        for (int o = 0; o < NOUT; o++) {
#pragma unroll
            for (int nt = 0; nt < 2; nt++) {
                int gn = n0 + nt * 16 + lm;
                float bv = (gn < Nc) ? biases[o][gn] : 0.f;
#pragma unroll
                for (int mt = 0; mt < 4; mt++)
#pragma unroll
                    for (int r = 0; r < 4; r++)
                        ep[(mt * 16 + lq * 4 + r) * ESTR + nt * 16 + lm] = f2bf(acc[o][mt][nt][r] + bv);
            }
#pragma unroll
            for (int it = 0; it < 4; it++) {
                int row = it * 16 + (lane >> 2);
                int cc = (lane & 3) * 8;
                bh8 v = *(const bh8*)(ep + row * ESTR + cc);
                int gm = m0 + row;
                int cg = n0 + cc;
                if (gm < M && cg < Nc) {
                    size_t cb = SPLIT40 ? (size_t)(cg + 24 * (cg / 40)) : (size_t)cg;
                    size_t rs = SPLIT40 ? 256 : (size_t)Nc;
                    *(bh8*)(Cs[o] + (size_t)gm * rs + cb) = v;
                }
            }
        }
    }

    // ---- folded-residual pass (waves 0-1), reuses LDS A ----
    if (HAS_EFF && w < 2) {
        int beoff[2];
#pragma unroll
        for (int nt = 0; nt < 2; nt++)
            beoff[nt] = (w * 32 + nt * 16 + lm) * KTOT + lq * 8;
        f32x4 acc_e[4][2];
#pragma unroll
        for (int i = 0; i < 4; i++)
#pragma unroll
            for (int j = 0; j < 2; j++)
                acc_e[i][j] = (f32x4){0.f, 0.f, 0.f, 0.f};
#pragma unroll
        for (int kc = 0; kc < KC; kc++) {
            bh8 af[4];
#pragma unroll
            for (int mt = 0; mt < 4; mt++)
                af[mt] = *(const bh8*)(As + (mt * 16 + lm) * LSTR + kc * 32 + lq * 8);
            bh8 be[2];
#pragma unroll
            for (int nt = 0; nt < 2; nt++)
                be[nt] = *(const bh8*)(Wte + beoff[nt] + kc * 32);
#pragma unroll
            for (int mt = 0; mt < 4; mt++)
#pragma unroll
                for (int nt = 0; nt < 2; nt++)
                    acc_e[mt][nt] = __builtin_amdgcn_mfma_f32_16x16x32_bf16(af[mt], be[nt], acc_e[mt][nt], 0, 0, 0);
        }
#pragma unroll
        for (int nt = 0; nt < 2; nt++) {
            int gn = w * 32 + nt * 16 + lm;
            if (gn >= 40) continue;
            float bv = biase[gn];
#pragma unroll
            for (int mt = 0; mt < 4; mt++)
#pragma unroll
                for (int r = 0; r < 4; r++) {
                    int gm = m0 + mt * 16 + lq * 4 + r;
                    if (gm < M) Ce[(size_t)gm * 40 + gn] = acc_e[mt][nt][r] + bv;
                }
        }
    }
}

// ---------------- GATv2 aggregation: QUARTER-WAVE per node, 4-edge deep pipeline ----------------
// Descending-degree perm (LPT). Per quarter: 4 edges per iteration with the
// next 4 edges' rows in flight (8x16B loads/lane outstanding) and indices
// prefetched one stage further. __launch_bounds__(256,4): VGPR cap 128,
// 16 waves/CU. bf16->f32 conversion redone on the fly (no f32 staging arrays).

__device__ __forceinline__ void us8_to_f(const us8 v, float* h) {
#pragma unroll
    for (int j = 0; j < 8; j++) h[j] = bf2f(v[j]);
}

template <int DVALID, bool FINAL, bool RES_INPLACE>
__global__ __launch_bounds__(256, 4) void gat_agg_quarter(
    const bf16_t* __restrict__ hs, const bf16_t* __restrict__ hd,
    const float* __restrict__ attn,
    const int* __restrict__ row_start, const int* __restrict__ src_sorted,
    const int* __restrict__ perm,
    bf16_t* __restrict__ P, float* __restrict__ out_final, int N)
{
    int w = threadIdx.x >> 6, lane = threadIdx.x & 63;
    int q = lane >> 4, ql = lane & 15;
    int gq = blockIdx.x * 16 + w * 4 + q;
    if (gq >= N) return;
    int n = perm[(N - 1) - gq];   // descending degree: LPT scheduling
    int f0 = ql * 16;         // padded feature base
    int h = ql >> 2;          // head
    int dp = (ql & 3) * 16;   // d within head (padded)

    float at[16], hdf[16];
#pragma unroll
    for (int j = 0; j < 16; j++)
        at[j] = (dp + j < DVALID) ? attn[h * DVALID + dp + j] : 0.f;
    {
        us8 a = *(const us8*)(hd + (unsigned)(n * 256 + f0));
        us8 b = *(const us8*)(hd + (unsigned)(n * 256 + f0 + 8));
        us8_to_f(a, hdf); us8_to_f(b, hdf + 8);
    }

    // per-node proxy center: logit at hs=0 (keeps exp args small; logits bounded)
    float pc;
    {
        float p = 0.f;
#pragma unroll
        for (int j = 0; j < 16; j++) {
            float qq = hdf[j];
            p += fmaxf(qq, SLOPE * qq) * at[j];
        }
        p += __shfl_xor(p, 1, 64);
        p += __shfl_xor(p, 2, 64);
        pc = p;
    }

    int s = row_start[n], e = row_start[n + 1];

    float cl = 0.f;
    float ca[16] = {};

    // process one gathered row (two us8) into (cl, ca); conversion on the fly
    auto proc = [&](const us8 ra, const us8 rb) {
        float p = 0.f;
#pragma unroll
        for (int j = 0; j < 8; j++) {
            float qa = bf2f(ra[j]) + hdf[j];
            p += fmaxf(qa, SLOPE * qa) * at[j];
            float qb = bf2f(rb[j]) + hdf[8 + j];
            p += fmaxf(qb, SLOPE * qb) * at[8 + j];
        }
        p += __shfl_xor(p, 1, 64);
        p += __shfl_xor(p, 2, 64);
        float wk = __expf(p - pc);
        cl += wk;
#pragma unroll
        for (int j = 0; j < 8; j++) {
            ca[j]     += wk * bf2f(ra[j]);
            ca[8 + j] += wk * bf2f(rb[j]);
        }
    };

#define GA(sn) (*(const us8*)(hs + (unsigned)((sn) * 256 + f0)))
#define GB(sn) (*(const us8*)(hs + (unsigned)((sn) * 256 + f0 + 8)))

    int i = s;
    if (i + 8 <= e) {
        int a0 = src_sorted[i], a1 = src_sorted[i + 1];
        int a2 = src_sorted[i + 2], a3 = src_sorted[i + 3];
        us8 c0a = GA(a0), c0b = GB(a0), c1a = GA(a1), c1b = GB(a1);
        us8 c2a = GA(a2), c2b = GB(a2), c3a = GA(a3), c3b = GB(a3);
        int b0 = src_sorted[i + 4], b1 = src_sorted[i + 5];
        int b2 = src_sorted[i + 6], b3 = src_sorted[i + 7];

        for (; i + 8 <= e; i += 4) {
            // issue next block's 8 gathers before current block's VALU
            us8 n0a = GA(b0), n0b = GB(b0), n1a = GA(b1), n1b = GB(b1);
            us8 n2a = GA(b2), n2b = GB(b2), n3a = GA(b3), n3b = GB(b3);
            // prefetch indices one further stage ahead
            if (i + 12 <= e) {
                b0 = src_sorted[i + 8];  b1 = src_sorted[i + 9];
                b2 = src_sorted[i + 10]; b3 = src_sorted[i + 11];
            }
            proc(c0a, c0b); proc(c1a, c1b); proc(c2a, c2b); proc(c3a, c3b);
            c0a = n0a; c0b = n0b; c1a = n1a; c1b = n1b;
            c2a = n2a; c2b = n2b; c3a = n3a; c3b = n3b;
        }
        // drain current block of 4
        proc(c0a, c0b); proc(c1a, c1b); proc(c2a, c2b); proc(c3a, c3b);
        i += 4;
    }
    // remainder (< 8 edges total, or < 4 tail after pipeline)
    for (; i + 2 <= e; i += 2) {
        int a0 = src_sorted[i], a1 = src_sorted[i + 1];
        us8 r0a = GA(a0), r0b = GB(a0), r1a = GA(a1), r1b = GB(a1);
        proc(r0a, r0b); proc(r1a, r1b);
    }
    if (i < e) {
        int a0 = src_sorted[i];
        us8 r0a = GA(a0), r0b = GB(a0);
        proc(r0a, r0b);
    }
#undef GA
#undef GB

    float v[16] = {};
    if (e > s) {
        float inv = 1.f / cl;
#pragma unroll
        for (int j = 0; j < 16; j++)
            v[j] = ca[j] * inv;
    }

    if (FINAL) {
        // head-sum: lanes ql, ql^4, ql^8, ql^12 hold the same d-range across heads
#pragma unroll
        for (int j = 0; j < 16; j++) {
            v[j] += __shfl_xor(v[j], 4, 64);
            v[j] += __shfl_xor(v[j], 8, 64);
        }
        if (h == 0) {
#pragma unroll
            for (int jj = 0; jj < 16; jj += 4) {
                if (dp + jj < DVALID) {   // DVALID % 4 == 0 -> whole float4 valid
                    float* op = out_final + (unsigned)(n * DVALID + dp + jj);
                    float4 cur = *(float4*)op;
                    cur.x += 0.25f * v[jj];
                    cur.y += 0.25f * v[jj + 1];
                    cur.z += 0.25f * v[jj + 2];
                    cur.w += 0.25f * v[jj + 3];
                    *(float4*)op = cur;
                }
            }
        }
    } else {
        unsigned oi = (unsigned)(n * 256 + f0);
        if (RES_INPLACE) {
            us8 pa = *(const us8*)(P + oi);
            us8 pb = *(const us8*)(P + oi + 8);
#pragma unroll
            for (int j = 0; j < 8; j++) {
                v[j] += bf2f(pa[j]);
                v[8 + j] += bf2f(pb[j]);
            }
        }
        us8 oa, ob;
#pragma unroll
        for (int j = 0; j < 8; j++) {
            oa[j] = f2bf(v[j]);
            ob[j] = f2bf(v[8 + j]);
        }
        *(us8*)(P + oi) = oa;
        *(us8*)(P + oi + 8) = ob;
    }
}

// ---------------- launch ----------------

extern "C" void kernel_launch(void* const* d_in, const int* in_sizes, int n_in,
                              void* d_out, int out_size, void* d_ws, size_t ws_size,
                              hipStream_t stream) {
    const float* x0    = (const float*)d_in[0];
    const int*   src   = (const int*)d_in[1];
    const int*   dst   = (const int*)d_in[2];
    const float* w_src0 = (const float*)d_in[3];  const float* b_src0 = (const float*)d_in[4];
    const float* w_dst0 = (const float*)d_in[5];  const float* b_dst0 = (const float*)d_in[6];
    const float* attn0  = (const float*)d_in[7];
    const float* w_res0 = (const float*)d_in[8];  const float* b_res0 = (const float*)d_in[9];
    const float* w_src1 = (const float*)d_in[10]; const float* b_src1 = (const float*)d_in[11];
    const float* w_dst1 = (const float*)d_in[12]; const float* b_dst1 = (const float*)d_in[13];
    const float* attn1  = (const float*)d_in[14];
    const float* w_src2 = (const float*)d_in[15]; const float* b_src2 = (const float*)d_in[16];
    const float* w_dst2 = (const float*)d_in[17]; const float* b_dst2 = (const float*)d_in[18];
    const float* attn2  = (const float*)d_in[19];
    const float* w_res2 = (const float*)d_in[20]; const float* b_res2 = (const float*)d_in[21];

    const int N = in_sizes[0] / 128;   // 50000
    const int E = in_sizes[1];         // 400000
    float* out = (float*)d_out;
    (void)n_in; (void)out_size; (void)ws_size;

    // ---- workspace (~80 MB) ----
    char* ws = (char*)d_ws;
    size_t off = 0;
    auto alloc = [&](size_t bytes) {
        void* q = ws + off;
        off = (off + bytes + 255) & ~(size_t)255;
        return q;
    };
    int* deg        = (int*)alloc((size_t)2 * N * 4);
    int* fill       = deg + N;
    int* bcnt       = (int*)alloc(256 * 4);     // 128 bucket counts + 128 fill
    int* bfill      = bcnt + 128;
    int* perm       = (int*)alloc((size_t)N * 4);
    int* row_start  = (int*)alloc((size_t)(N + 1) * 4);
    int* chunk_sums = (int*)alloc(256 * 4);
    int* src_sorted = (int*)alloc((size_t)E * 4);
    bf16_t* t_src0 = (bf16_t*)alloc(256 * 128 * 2);
    bf16_t* t_dst0 = (bf16_t*)alloc(256 * 128 * 2);
    bf16_t* t_res0 = (bf16_t*)alloc(256 * 128 * 2);
    bf16_t* t_src1 = (bf16_t*)alloc(256 * 256 * 2);
    bf16_t* t_dst1 = (bf16_t*)alloc(256 * 256 * 2);
    bf16_t* t_src2 = (bf16_t*)alloc(192 * 256 * 2);
    bf16_t* t_dst2 = (bf16_t*)alloc(192 * 256 * 2);
    bf16_t* t_eff  = (bf16_t*)alloc(64 * 256 * 2);
    float*  b_eff  = (float*)alloc(64 * 4);
    const size_t elems = (size_t)N * 256;
    bf16_t* P  = (bf16_t*)alloc(elems * 2);
    bf16_t* HS = (bf16_t*)alloc(elems * 2);
    bf16_t* HD = (bf16_t*)alloc(elems * 2);

    // ---- CSR build + degree sort + weight conversion ----
    hipMemsetAsync(deg, 0, (size_t)2 * N * 4, stream);
    hipMemsetAsync(bcnt, 0, 256 * 4, stream);
    int eblocks = (E + 255) / 256;     // 1563
    int nchunks = (N + 1023) / 1024;   // 49 (<= 64 required by scan_write)
    hipLaunchKernelGGL(hist_and_convert, dim3(eblocks + 1344), dim3(256), 0, stream,
                       dst, E, eblocks, deg,
                       w_src0, w_dst0, w_res0, w_src1, w_dst1, w_src2, w_dst2, w_res2, b_res2,
                       t_src0, t_dst0, t_res0, t_src1, t_dst1, t_src2, t_dst2, t_eff, b_eff);
    hipLaunchKernelGGL(deg_chunk_sum, dim3(nchunks), dim3(256), 0, stream, deg, N, chunk_sums, bcnt);
    hipLaunchKernelGGL(scan_write, dim3(nchunks), dim3(256), 0, stream, deg, N, chunk_sums,
                       row_start, E, bcnt, bfill, perm);

    dim3 blk(256);
    int mtiles = (N + 63) / 64;        // 782
    int ab = (N + 15) / 16;            // 3125 (quarter-wave-per-node agg)

    // ---- Layer 0: fused hs|hd|res GEMM from x0, OVERLAPPED with edge scatter ----
    hipLaunchKernelGGL((gemm_lds<float, 3, 128, 256, false, false, true>),
                       dim3(mtiles + eblocks), blk, 0, stream,
                       x0, t_src0, t_dst0, t_res0, b_src0, b_dst0, b_res0,
                       HS, HD, P,
                       (const bf16_t*)nullptr, (const float*)nullptr, (float*)nullptr,
                       N, 256,
                       dst, src, E, row_start, fill, src_sorted, mtiles);
    hipLaunchKernelGGL((gat_agg_quarter<64, false, true>), dim3(ab), blk, 0, stream,
                       HS, HD, attn0, row_start, src_sorted, perm, P, (float*)nullptr, N);

    // ---- Layer 1: fused hs|hd from P; identity residual in-place ----
    hipLaunchKernelGGL((gemm_lds<bf16_t, 2, 256, 256, false, false, false>), dim3(mtiles), blk, 0, stream,
                       P, t_src1, t_dst1, (const bf16_t*)nullptr, b_src1, b_dst1, (const float*)nullptr,
                       HS, HD, (bf16_t*)nullptr,
                       (const bf16_t*)nullptr, (const float*)nullptr, (float*)nullptr,
                       N, 256,
                       (const int*)nullptr, (const int*)nullptr, 0,
                       (const int*)nullptr, (int*)nullptr, (int*)nullptr, 0);
    hipLaunchKernelGGL((gat_agg_quarter<64, false, true>), dim3(ab), blk, 0, stream,
                       HS, HD, attn1, row_start, src_sorted, perm, P, (float*)nullptr, N);

    // ---- Layer 2: fused hs|hd (SPLIT40) + eff residual (f32 -> out); FINAL agg accumulates ----
    hipLaunchKernelGGL((gemm_lds<bf16_t, 2, 256, 192, true, true, false>), dim3(mtiles), blk, 0, stream,
                       P, t_src2, t_dst2, (const bf16_t*)nullptr, b_src2, b_dst2, (const float*)nullptr,
                       HS, HD, (bf16_t*)nullptr,
                       t_eff, b_eff, out,
                       N, 160,
                       (const int*)nullptr, (const int*)nullptr, 0,
                       (const int*)nullptr, (int*)nullptr, (int*)nullptr, 0);
    hipLaunchKernelGGL((gat_agg_quarter<40, true, false>), dim3(ab), blk, 0, stream,
                       HS, HD, attn2, row_start, src_sorted, perm, (bf16_t*)nullptr, out, N);
}

// Round 16
// 443.392 us; speedup vs baseline: 1.3467x; 1.3467x over previous
//
#include <hip/hip_runtime.h>
#include <hip/hip_bf16.h>
#include <math.h>

// N=50000, E=400000, F_IN=128, HID=64, OUT=40, H=4
#define SLOPE 0.2f

typedef unsigned short bf16_t;
typedef short bh8 __attribute__((ext_vector_type(8)));
typedef unsigned short us8 __attribute__((ext_vector_type(8)));
typedef float f32x4 __attribute__((ext_vector_type(4)));

__device__ __forceinline__ float bf2f(bf16_t x) {
    return __uint_as_float((unsigned)x << 16);
}
__device__ __forceinline__ bf16_t f2bf(float v) {
    unsigned u = __float_as_uint(v);
    return (bf16_t)((u + 0x7FFFu + ((u >> 16) & 1u)) >> 16);  // RNE
}
__device__ __forceinline__ ushort2 pk_f2bf(float a, float b) {
    __hip_bfloat162 h2 = __float22bfloat162_rn(float2{a, b});  // v_cvt_pk_bf16_f32
    union { __hip_bfloat162 h; ushort2 u; } u;
    u.h = h2;
    return u.u;
}

// ---------------- fused histogram + weight conversion (R15/R16-verified) ----------------

__global__ void hist_and_convert(
    const int* __restrict__ dst, int E, int eblocks, int* __restrict__ deg,
    const float* __restrict__ w0, const float* __restrict__ w1, const float* __restrict__ w2,
    const float* __restrict__ w3, const float* __restrict__ w4,
    const float* __restrict__ w5, const float* __restrict__ w6,
    const float* __restrict__ wr2, const float* __restrict__ br2,
    bf16_t* __restrict__ t0, bf16_t* __restrict__ t1, bf16_t* __restrict__ t2,
    bf16_t* __restrict__ t3, bf16_t* __restrict__ t4,
    bf16_t* __restrict__ t5, bf16_t* __restrict__ t6,
    bf16_t* __restrict__ teff, float* __restrict__ b_eff)
{
    int t = threadIdx.x;
    if ((int)blockIdx.x < eblocks) {
        int e = blockIdx.x * 256 + t;
        if (e < E) atomicAdd(&deg[dst[e]], 1);
        return;
    }
    int b = blockIdx.x - eblocks;
    const float* W; bf16_t* T; int K, Nc, lb;
    if (b < 384) {
        int g = b / 128; lb = b - g * 128;
        W = g == 0 ? w0 : (g == 1 ? w1 : w2);
        T = g == 0 ? t0 : (g == 1 ? t1 : t2);
        K = 128; Nc = 256;
    } else if (b < 896) {
        int g = (b - 384) / 256; lb = (b - 384) - g * 256;
        W = g == 0 ? w3 : w4; T = g == 0 ? t3 : t4;
        K = 256; Nc = 256;
    } else if (b < 1280) {
        int g = (b - 896) / 192; lb = (b - 896) - g * 192;
        W = g == 0 ? w5 : w6; T = g == 0 ? t5 : t6;
        K = 256; Nc = 160;
    } else {
        lb = b - 1280;
        int idx = lb * 256 + t;          // 64*256 = 16384 elems
        int n = idx >> 8, k = idx & 255;
        float v = 0.f;
        if (n < 40)
            v = 0.25f * (wr2[(size_t)k * 160 + n] + wr2[(size_t)k * 160 + 40 + n] +
                         wr2[(size_t)k * 160 + 80 + n] + wr2[(size_t)k * 160 + 120 + n]);
        teff[idx] = f2bf(v);
        if (lb == 0 && t < 40)
            b_eff[t] = 0.25f * (br2[t] + br2[40 + t] + br2[80 + t] + br2[120 + t]);
        return;
    }
    int idx = lb * 256 + t;
    int n = idx / K, k = idx - n * K;
    float v = (n < Nc) ? W[(size_t)k * Nc + n] : 0.f;
    T[idx] = f2bf(v);
}

// ---------------- CSR scan + degree-bucket sort ----------------
// deg_chunk_sum additionally builds a 128-bucket degree histogram (LDS-staged).

__global__ void deg_chunk_sum(const int* __restrict__ deg, int n,
                              int* __restrict__ chunk_sums, int* __restrict__ bcnt) {
    __shared__ int sm[256];
    __shared__ int hl[128];
    int t = threadIdx.x;
    if (t < 128) hl[t] = 0;
    __syncthreads();
    int base = blockIdx.x * 1024;
    int s = 0;
    for (int i = t; i < 1024; i += 256) {
        int idx = base + i;
        if (idx < n) {
            int d = deg[idx];
            s += d;
            atomicAdd(&hl[d < 127 ? d : 127], 1);
        }
    }
    sm[t] = s;
    __syncthreads();
    for (int off = 128; off > 0; off >>= 1) {
        if (t < off) sm[t] += sm[t + off];
        __syncthreads();
    }
    if (t == 0) chunk_sums[blockIdx.x] = sm[0];
    if (t < 128 && hl[t]) atomicAdd(&bcnt[t], hl[t]);
}

// scan_write: row_start prefix (as before) + degree-sorted node permutation.
// Counting sort: per-block LDS rank within bucket, one global atomic per
// bucket per block, then scatter perm[sbase[b]+gbase[b]+rank] = node.
__global__ void scan_write(const int* __restrict__ deg, int n,
                           const int* __restrict__ chunk_sums,
                           int* __restrict__ row_start, int Etot,
                           const int* __restrict__ bcnt, int* __restrict__ bfill,
                           int* __restrict__ perm) {
    __shared__ int sm[256];
    __shared__ int s_pref;
    __shared__ int sbase[128];
    __shared__ int lcnt[128];
    __shared__ int gbase[128];
    int base = blockIdx.x * 1024;
    int t = threadIdx.x;

    if (t < 128) lcnt[t] = 0;

    // wave 0: sum chunk_sums[0..blockIdx.x) via wave-reduce
    if (t < 64) {
        int v = (t < (int)blockIdx.x) ? chunk_sums[t] : 0;
#pragma unroll
        for (int off = 32; off > 0; off >>= 1)
            v += __shfl_down(v, off, 64);
        if (t == 0) s_pref = v;
    }
    // thread 128: serial exclusive prefix of the 128-bucket histogram
    if (t == 128) {
        int run = 0;
        for (int i = 0; i < 128; i++) { sbase[i] = run; run += bcnt[i]; }
    }

    int vv[4];
    int tsum = 0;
#pragma unroll
    for (int j = 0; j < 4; j++) {
        int idx = base + t * 4 + j;
        vv[j] = (idx < n) ? deg[idx] : 0;
        tsum += vv[j];
    }
    sm[t] = tsum;
    __syncthreads();
    for (int off = 1; off < 256; off <<= 1) {
        int x = (t >= off) ? sm[t - off] : 0;
        __syncthreads();
        sm[t] += x;
        __syncthreads();
    }
    int excl = sm[t] - tsum + s_pref;
#pragma unroll
    for (int j = 0; j < 4; j++) {
        int idx = base + t * 4 + j;
        if (idx < n) row_start[idx] = excl;
        excl += vv[j];
    }
    if (blockIdx.x == 0 && t == 0) row_start[n] = Etot;

    // ---- degree-bucket scatter ----
    int rnk[4], bb[4];
#pragma unroll
    for (int j = 0; j < 4; j++) {
        int idx = base + t * 4 + j;
        if (idx < n) {
            bb[j] = vv[j] < 127 ? vv[j] : 127;
            rnk[j] = atomicAdd(&lcnt[bb[j]], 1);
        } else bb[j] = -1;
    }
    __syncthreads();
    if (t < 128 && lcnt[t]) gbase[t] = atomicAdd(&bfill[t], lcnt[t]);
    __syncthreads();
#pragma unroll
    for (int j = 0; j < 4; j++) {
        int idx = base + t * 4 + j;
        if (bb[j] >= 0)
            perm[sbase[bb[j]] + gbase[bb[j]] + rnk[j]] = idx;
    }
}

// ---------------- single-A-stage multi-output MFMA GEMM (R14/R17 config) ----------------
// DO_SCATTER: blocks [mtiles, mtiles+eblocks) run the edge scatter (independent
// work overlapped with the layer-0 GEMM in one dispatch) and return early.

template <typename TA, int NOUT, int KTOT, int NPAD, bool SPLIT40, bool HAS_EFF, bool DO_SCATTER>
__global__ __launch_bounds__(256) void gemm_lds(
    const TA* __restrict__ A,
    const bf16_t* __restrict__ Wt0, const bf16_t* __restrict__ Wt1, const bf16_t* __restrict__ Wt2,
    const float* __restrict__ bias0, const float* __restrict__ bias1, const float* __restrict__ bias2,
    bf16_t* __restrict__ C0, bf16_t* __restrict__ C1, bf16_t* __restrict__ C2,
    const bf16_t* __restrict__ Wte, const float* __restrict__ biase, float* __restrict__ Ce,
    int M, int Nc,
    const int* __restrict__ e_dst, const int* __restrict__ e_src, int E,
    const int* __restrict__ row_start, int* __restrict__ fill,
    int* __restrict__ src_sorted, int mtiles)
{
    constexpr int LSTR = KTOT + 8;     // stage row stride
    constexpr int ESTR = 38;           // epilogue row stride
    constexpr int KC = KTOT / 32;
    __shared__ bf16_t As[64 * LSTR];
    __shared__ bf16_t Ep[4 * 64 * ESTR];

    int tid = threadIdx.x;

    if (DO_SCATTER && (int)blockIdx.x >= mtiles) {
        int e = (blockIdx.x - mtiles) * 256 + tid;
        if (e < E) {
            int d_ = e_dst[e];
            int pos = row_start[d_] + atomicAdd(&fill[d_], 1);
            src_sorted[pos] = e_src[e];
        }
        return;
    }

    int lane = tid & 63, w = tid >> 6;
    int lm = lane & 15, lq = lane >> 4;
    int m0 = blockIdx.x * 64;

    const bf16_t* Wts[3] = {Wt0, Wt1, Wt2};
    const float* biases[3] = {bias0, bias1, bias2};
    bf16_t* Cs[3] = {C0, C1, C2};

    // ---- stage A slab (64 rows x KTOT) once ----
    if (sizeof(TA) == 4) {            // KTOT == 128, f32 input
#pragma unroll
        for (int it = 0; it < 4; it++) {
            int idx = tid + it * 256;  // 1024 chunks of 8 floats
            int r = idx >> 4, c = idx & 15;
            int gm = m0 + r; if (gm >= M) gm = M - 1;
            const float* ap = (const float*)A + (size_t)gm * KTOT + c * 8;
            float4 lo = *(const float4*)ap;
            float4 hi = *(const float4*)(ap + 4);
            ushort2 p0 = pk_f2bf(lo.x, lo.y), p1 = pk_f2bf(lo.z, lo.w);
            ushort2 p2 = pk_f2bf(hi.x, hi.y), p3 = pk_f2bf(hi.z, hi.w);
            bh8 v = { (short)p0.x, (short)p0.y, (short)p1.x, (short)p1.y,
                      (short)p2.x, (short)p2.y, (short)p3.x, (short)p3.y };
            *(bh8*)(As + r * LSTR + c * 8) = v;
        }
    } else {                           // KTOT == 256, bf16 input
#pragma unroll
        for (int it = 0; it < 8; it++) {
            int idx = tid + it * 256;  // 2048 chunks of 8 bf16
            int r = idx >> 5, c = idx & 31;
            int gm = m0 + r; if (gm >= M) gm = M - 1;
            bh8 v = *(const bh8*)((const bf16_t*)A + (size_t)gm * KTOT + c * 8);
            *(bh8*)(As + r * LSTR + c * 8) = v;
        }
    }
    __syncthreads();   // the ONLY barrier

    bf16_t* ep = Ep + w * (64 * ESTR);
    constexpr int NCHUNK = (NPAD + 127) / 128;

#pragma unroll
    for (int chunk = 0; chunk < NCHUNK; chunk++) {
        int n0 = chunk * 128 + w * 32;
        if (n0 >= NPAD) continue;      // no barriers inside -> safe

        int boff[NOUT][2];
#pragma unroll
        for (int o = 0; o < NOUT; o++)
#pragma unroll
            for (int nt = 0; nt < 2; nt++)
                boff[o][nt] = (n0 + nt * 16 + lm) * KTOT + lq * 8;

        f32x4 acc[NOUT][4][2];
#pragma unroll
        for (int o = 0; o < NOUT; o++)
#pragma unroll
            for (int i = 0; i < 4; i++)
#pragma unroll
                for (int j = 0; j < 2; j++)
                    acc[o][i][j] = (f32x4){0.f, 0.f, 0.f, 0.f};

        bh8 bf_cur[NOUT][2], bf_nxt[NOUT][2];
#pragma unroll
        for (int o = 0; o < NOUT; o++)
#pragma unroll
            for (int nt = 0; nt < 2; nt++)
                bf_cur[o][nt] = *(const bh8*)(Wts[o] + boff[o][nt]);

#pragma unroll
        for (int kc = 0; kc < KC; kc++) {
            if (kc + 1 < KC) {
#pragma unroll
                for (int o = 0; o < NOUT; o++)
#pragma unroll
                    for (int nt = 0; nt < 2; nt++)
                        bf_nxt[o][nt] = *(const bh8*)(Wts[o] + boff[o][nt] + (kc + 1) * 32);
            }
            bh8 af[4];
#pragma unroll
            for (int mt = 0; mt < 4; mt++)
                af[mt] = *(const bh8*)(As + (mt * 16 + lm) * LSTR + kc * 32 + lq * 8);
#pragma unroll
            for (int o = 0; o < NOUT; o++)
#pragma unroll
                for (int mt = 0; mt < 4; mt++)
#pragma unroll
                    for (int nt = 0; nt < 2; nt++)
                        acc[o][mt][nt] = __builtin_amdgcn_mfma_f32_16x16x32_bf16(af[mt], bf_cur[o][nt], acc[o][mt][nt], 0, 0, 0);
            if (kc + 1 < KC) {
#pragma unroll
                for (int o = 0; o < NOUT; o++)
#pragma unroll
                    for (int nt = 0; nt < 2; nt++)
                        bf_cur[o][nt] = bf_nxt[o][nt];
            }
        }

        // ---- per-wave epilogue: private LDS tile -> full-line global stores ----
#pragma unroll
        for (int o = 0; o < NOUT; o++) {
#pragma unroll
            for (int nt = 0; nt < 2; nt++) {
                int gn = n0 + nt * 16 + lm;
                float bv = (gn < Nc) ? biases[o][gn] : 0.f;
#pragma unroll
                for (int mt = 0; mt < 4; mt++)
#pragma unroll
                    for (int r = 0; r < 4; r++)
                        ep[(mt * 16 + lq * 4 + r) * ESTR + nt * 16 + lm] = f2bf(acc[o][mt][nt][r] + bv);
            }
#pragma unroll
            for (int it = 0; it < 4; it++) {
                int row = it * 16 + (lane >> 2);
                int cc = (lane & 3) * 8;
                bh8 v = *(const bh8*)(ep + row * ESTR + cc);
                int gm = m0 + row;
                int cg = n0 + cc;
                if (gm < M && cg < Nc) {
                    size_t cb = SPLIT40 ? (size_t)(cg + 24 * (cg / 40)) : (size_t)cg;
                    size_t rs = SPLIT40 ? 256 : (size_t)Nc;
                    *(bh8*)(Cs[o] + (size_t)gm * rs + cb) = v;
                }
            }
        }
    }

    // ---- folded-residual pass (waves 0-1), reuses LDS A ----
    if (HAS_EFF && w < 2) {
        int beoff[2];
#pragma unroll
        for (int nt = 0; nt < 2; nt++)
            beoff[nt] = (w * 32 + nt * 16 + lm) * KTOT + lq * 8;
        f32x4 acc_e[4][2];
#pragma unroll
        for (int i = 0; i < 4; i++)
#pragma unroll
            for (int j = 0; j < 2; j++)
                acc_e[i][j] = (f32x4){0.f, 0.f, 0.f, 0.f};
#pragma unroll
        for (int kc = 0; kc < KC; kc++) {
            bh8 af[4];
#pragma unroll
            for (int mt = 0; mt < 4; mt++)
                af[mt] = *(const bh8*)(As + (mt * 16 + lm) * LSTR + kc * 32 + lq * 8);
            bh8 be[2];
#pragma unroll
            for (int nt = 0; nt < 2; nt++)
                be[nt] = *(const bh8*)(Wte + beoff[nt] + kc * 32);
#pragma unroll
            for (int mt = 0; mt < 4; mt++)
#pragma unroll
                for (int nt = 0; nt < 2; nt++)
                    acc_e[mt][nt] = __builtin_amdgcn_mfma_f32_16x16x32_bf16(af[mt], be[nt], acc_e[mt][nt], 0, 0, 0);
        }
#pragma unroll
        for (int nt = 0; nt < 2; nt++) {
            int gn = w * 32 + nt * 16 + lm;
            if (gn >= 40) continue;
            float bv = biase[gn];
#pragma unroll
            for (int mt = 0; mt < 4; mt++)
#pragma unroll
                for (int r = 0; r < 4; r++) {
                    int gm = m0 + mt * 16 + lq * 4 + r;
                    if (gm < M) Ce[(size_t)gm * 40 + gn] = acc_e[mt][nt][r] + bv;
                }
        }
    }
}

// ---------------- GATv2 aggregation: QUARTER-WAVE per node, 2-edge pipeline, spill-free ----------------
// R13 post-mortem: 4-edge pipeline = ~150 live VGPR > 128 cap -> forced spills
// (WRITE_SIZE 224MB scratch). This version: 2-edge prefetch (8 us8 = 32 VGPR),
// on-the-fly bf16 conversion (no f32 staging arrays), single accumulator set
// -> ~90 live VGPR, fits under the 128 cap of __launch_bounds__(256,4).

__device__ __forceinline__ void us8_to_f(const us8 v, float* h) {
#pragma unroll
    for (int j = 0; j < 8; j++) h[j] = bf2f(v[j]);
}

template <int DVALID, bool FINAL, bool RES_INPLACE>
__global__ __launch_bounds__(256, 4) void gat_agg_quarter(
    const bf16_t* __restrict__ hs, const bf16_t* __restrict__ hd,
    const float* __restrict__ attn,
    const int* __restrict__ row_start, const int* __restrict__ src_sorted,
    const int* __restrict__ perm,
    bf16_t* __restrict__ P, float* __restrict__ out_final, int N)
{
    int w = threadIdx.x >> 6, lane = threadIdx.x & 63;
    int q = lane >> 4, ql = lane & 15;
    int gq = blockIdx.x * 16 + w * 4 + q;
    if (gq >= N) return;
    int n = perm[(N - 1) - gq];   // descending degree: LPT scheduling
    int f0 = ql * 16;         // padded feature base
    int h = ql >> 2;          // head
    int dp = (ql & 3) * 16;   // d within head (padded)

    float at[16], hdf[16];
#pragma unroll
    for (int j = 0; j < 16; j++)
        at[j] = (dp + j < DVALID) ? attn[h * DVALID + dp + j] : 0.f;
    {
        us8 a = *(const us8*)(hd + (unsigned)(n * 256 + f0));
        us8 b = *(const us8*)(hd + (unsigned)(n * 256 + f0 + 8));
        us8_to_f(a, hdf); us8_to_f(b, hdf + 8);
    }

    // per-node proxy center: logit at hs=0 (keeps exp args small; logits bounded)
    float pc;
    {
        float p = 0.f;
#pragma unroll
        for (int j = 0; j < 16; j++) {
            float qq = hdf[j];
            p += fmaxf(qq, SLOPE * qq) * at[j];
        }
        p += __shfl_xor(p, 1, 64);
        p += __shfl_xor(p, 2, 64);
        pc = p;
    }

    int s = row_start[n], e = row_start[n + 1];

    float cl = 0.f;
    float ca[16] = {};

    // process one gathered row (two us8) into (cl, ca); conversion on the fly
    auto proc = [&](const us8 ra, const us8 rb) {
        float p = 0.f;
#pragma unroll
        for (int j = 0; j < 8; j++) {
            float qa = bf2f(ra[j]) + hdf[j];
            p += fmaxf(qa, SLOPE * qa) * at[j];
            float qb = bf2f(rb[j]) + hdf[8 + j];
            p += fmaxf(qb, SLOPE * qb) * at[8 + j];
        }
        p += __shfl_xor(p, 1, 64);
        p += __shfl_xor(p, 2, 64);
        float wk = __expf(p - pc);
        cl += wk;
#pragma unroll
        for (int j = 0; j < 8; j++) {
            ca[j]     += wk * bf2f(ra[j]);
            ca[8 + j] += wk * bf2f(rb[j]);
        }
    };

#define GA(sn) (*(const us8*)(hs + (unsigned)((sn) * 256 + f0)))
#define GB(sn) (*(const us8*)(hs + (unsigned)((sn) * 256 + f0 + 8)))

    int i = s;
    if (i + 4 <= e) {
        int a0 = src_sorted[i], a1 = src_sorted[i + 1];
        us8 c0a = GA(a0), c0b = GB(a0), c1a = GA(a1), c1b = GB(a1);
        int b0 = src_sorted[i + 2], b1 = src_sorted[i + 3];

        for (; i + 4 <= e; i += 2) {
            // issue next pair's 4 gathers before current pair's VALU
            us8 n0a = GA(b0), n0b = GB(b0), n1a = GA(b1), n1b = GB(b1);
            // prefetch indices one stage further ahead
            if (i + 6 <= e) { b0 = src_sorted[i + 4]; b1 = src_sorted[i + 5]; }
            proc(c0a, c0b); proc(c1a, c1b);
            c0a = n0a; c0b = n0b; c1a = n1a; c1b = n1b;
        }
        // drain current pair
        proc(c0a, c0b); proc(c1a, c1b);
        i += 2;
    }
    // remainder (< 4 edges total, or <= 1 tail after pipeline)
    for (; i + 2 <= e; i += 2) {
        int a0 = src_sorted[i], a1 = src_sorted[i + 1];
        us8 r0a = GA(a0), r0b = GB(a0), r1a = GA(a1), r1b = GB(a1);
        proc(r0a, r0b); proc(r1a, r1b);
    }
    if (i < e) {
        int a0 = src_sorted[i];
        us8 r0a = GA(a0), r0b = GB(a0);
        proc(r0a, r0b);
    }
#undef GA
#undef GB

    float v[16] = {};
    if (e > s) {
        float inv = 1.f / cl;
#pragma unroll
        for (int j = 0; j < 16; j++)
            v[j] = ca[j] * inv;
    }

    if (FINAL) {
        // head-sum: lanes ql, ql^4, ql^8, ql^12 hold the same d-range across heads
#pragma unroll
        for (int j = 0; j < 16; j++) {
            v[j] += __shfl_xor(v[j], 4, 64);
            v[j] += __shfl_xor(v[j], 8, 64);
        }
        if (h == 0) {
#pragma unroll
            for (int jj = 0; jj < 16; jj += 4) {
                if (dp + jj < DVALID) {   // DVALID % 4 == 0 -> whole float4 valid
                    float* op = out_final + (unsigned)(n * DVALID + dp + jj);
                    float4 cur = *(float4*)op;
                    cur.x += 0.25f * v[jj];
                    cur.y += 0.25f * v[jj + 1];
                    cur.z += 0.25f * v[jj + 2];
                    cur.w += 0.25f * v[jj + 3];
                    *(float4*)op = cur;
                }
            }
        }
    } else {
        unsigned oi = (unsigned)(n * 256 + f0);
        if (RES_INPLACE) {
            us8 pa = *(const us8*)(P + oi);
            us8 pb = *(const us8*)(P + oi + 8);
#pragma unroll
            for (int j = 0; j < 8; j++) {
                v[j] += bf2f(pa[j]);
                v[8 + j] += bf2f(pb[j]);
            }
        }
        us8 oa, ob;
#pragma unroll
        for (int j = 0; j < 8; j++) {
            oa[j] = f2bf(v[j]);
            ob[j] = f2bf(v[8 + j]);
        }
        *(us8*)(P + oi) = oa;
        *(us8*)(P + oi + 8) = ob;
    }
}

// ---------------- launch ----------------

extern "C" void kernel_launch(void* const* d_in, const int* in_sizes, int n_in,
                              void* d_out, int out_size, void* d_ws, size_t ws_size,
                              hipStream_t stream) {
    const float* x0    = (const float*)d_in[0];
    const int*   src   = (const int*)d_in[1];
    const int*   dst   = (const int*)d_in[2];
    const float* w_src0 = (const float*)d_in[3];  const float* b_src0 = (const float*)d_in[4];
    const float* w_dst0 = (const float*)d_in[5];  const float* b_dst0 = (const float*)d_in[6];
    const float* attn0  = (const float*)d_in[7];
    const float* w_res0 = (const float*)d_in[8];  const float* b_res0 = (const float*)d_in[9];
    const float* w_src1 = (const float*)d_in[10]; const float* b_src1 = (const float*)d_in[11];
    const float* w_dst1 = (const float*)d_in[12]; const float* b_dst1 = (const float*)d_in[13];
    const float* attn1  = (const float*)d_in[14];
    const float* w_src2 = (const float*)d_in[15]; const float* b_src2 = (const float*)d_in[16];
    const float* w_dst2 = (const float*)d_in[17]; const float* b_dst2 = (const float*)d_in[18];
    const float* attn2  = (const float*)d_in[19];
    const float* w_res2 = (const float*)d_in[20]; const float* b_res2 = (const float*)d_in[21];

    const int N = in_sizes[0] / 128;   // 50000
    const int E = in_sizes[1];         // 400000
    float* out = (float*)d_out;
    (void)n_in; (void)out_size; (void)ws_size;

    // ---- workspace (~80 MB) ----
    char* ws = (char*)d_ws;
    size_t off = 0;
    auto alloc = [&](size_t bytes) {
        void* q = ws + off;
        off = (off + bytes + 255) & ~(size_t)255;
        return q;
    };
    int* deg        = (int*)alloc((size_t)2 * N * 4);
    int* fill       = deg + N;
    int* bcnt       = (int*)alloc(256 * 4);     // 128 bucket counts + 128 fill
    int* bfill      = bcnt + 128;
    int* perm       = (int*)alloc((size_t)N * 4);
    int* row_start  = (int*)alloc((size_t)(N + 1) * 4);
    int* chunk_sums = (int*)alloc(256 * 4);
    int* src_sorted = (int*)alloc((size_t)E * 4);
    bf16_t* t_src0 = (bf16_t*)alloc(256 * 128 * 2);
    bf16_t* t_dst0 = (bf16_t*)alloc(256 * 128 * 2);
    bf16_t* t_res0 = (bf16_t*)alloc(256 * 128 * 2);
    bf16_t* t_src1 = (bf16_t*)alloc(256 * 256 * 2);
    bf16_t* t_dst1 = (bf16_t*)alloc(256 * 256 * 2);
    bf16_t* t_src2 = (bf16_t*)alloc(192 * 256 * 2);
    bf16_t* t_dst2 = (bf16_t*)alloc(192 * 256 * 2);
    bf16_t* t_eff  = (bf16_t*)alloc(64 * 256 * 2);
    float*  b_eff  = (float*)alloc(64 * 4);
    const size_t elems = (size_t)N * 256;
    bf16_t* P  = (bf16_t*)alloc(elems * 2);
    bf16_t* HS = (bf16_t*)alloc(elems * 2);
    bf16_t* HD = (bf16_t*)alloc(elems * 2);

    // ---- CSR build + degree sort + weight conversion ----
    hipMemsetAsync(deg, 0, (size_t)2 * N * 4, stream);
    hipMemsetAsync(bcnt, 0, 256 * 4, stream);
    int eblocks = (E + 255) / 256;     // 1563
    int nchunks = (N + 1023) / 1024;   // 49 (<= 64 required by scan_write)
    hipLaunchKernelGGL(hist_and_convert, dim3(eblocks + 1344), dim3(256), 0, stream,
                       dst, E, eblocks, deg,
                       w_src0, w_dst0, w_res0, w_src1, w_dst1, w_src2, w_dst2, w_res2, b_res2,
                       t_src0, t_dst0, t_res0, t_src1, t_dst1, t_src2, t_dst2, t_eff, b_eff);
    hipLaunchKernelGGL(deg_chunk_sum, dim3(nchunks), dim3(256), 0, stream, deg, N, chunk_sums, bcnt);
    hipLaunchKernelGGL(scan_write, dim3(nchunks), dim3(256), 0, stream, deg, N, chunk_sums,
                       row_start, E, bcnt, bfill, perm);

    dim3 blk(256);
    int mtiles = (N + 63) / 64;        // 782
    int ab = (N + 15) / 16;            // 3125 (quarter-wave-per-node agg)

    // ---- Layer 0: fused hs|hd|res GEMM from x0, OVERLAPPED with edge scatter ----
    hipLaunchKernelGGL((gemm_lds<float, 3, 128, 256, false, false, true>),
                       dim3(mtiles + eblocks), blk, 0, stream,
                       x0, t_src0, t_dst0, t_res0, b_src0, b_dst0, b_res0,
                       HS, HD, P,
                       (const bf16_t*)nullptr, (const float*)nullptr, (float*)nullptr,
                       N, 256,
                       dst, src, E, row_start, fill, src_sorted, mtiles);
    hipLaunchKernelGGL((gat_agg_quarter<64, false, true>), dim3(ab), blk, 0, stream,
                       HS, HD, attn0, row_start, src_sorted, perm, P, (float*)nullptr, N);

    // ---- Layer 1: fused hs|hd from P; identity residual in-place ----
    hipLaunchKernelGGL((gemm_lds<bf16_t, 2, 256, 256, false, false, false>), dim3(mtiles), blk, 0, stream,
                       P, t_src1, t_dst1, (const bf16_t*)nullptr, b_src1, b_dst1, (const float*)nullptr,
                       HS, HD, (bf16_t*)nullptr,
                       (const bf16_t*)nullptr, (const float*)nullptr, (float*)nullptr,
                       N, 256,
                       (const int*)nullptr, (const int*)nullptr, 0,
                       (const int*)nullptr, (int*)nullptr, (int*)nullptr, 0);
    hipLaunchKernelGGL((gat_agg_quarter<64, false, true>), dim3(ab), blk, 0, stream,
                       HS, HD, attn1, row_start, src_sorted, perm, P, (float*)nullptr, N);

    // ---- Layer 2: fused hs|hd (SPLIT40) + eff residual (f32 -> out); FINAL agg accumulates ----
    hipLaunchKernelGGL((gemm_lds<bf16_t, 2, 256, 192, true, true, false>), dim3(mtiles), blk, 0, stream,
                       P, t_src2, t_dst2, (const bf16_t*)nullptr, b_src2, b_dst2, (const float*)nullptr,
                       HS, HD, (bf16_t*)nullptr,
                       t_eff, b_eff, out,
                       N, 160,
                       (const int*)nullptr, (const int*)nullptr, 0,
                       (const int*)nullptr, (int*)nullptr, (int*)nullptr, 0);
    hipLaunchKernelGGL((gat_agg_quarter<40, true, false>), dim3(ab), blk, 0, stream,
                       HS, HD, attn2, row_start, src_sorted, perm, (bf16_t*)nullptr, out, N);
}

// Round 17
// 401.787 us; speedup vs baseline: 1.4862x; 1.1035x over previous
//
#include <hip/hip_runtime.h>
#include <hip/hip_bf16.h>
#include <math.h>

// N=50000, E=400000, F_IN=128, HID=64, OUT=40, H=4
#define SLOPE 0.2f

typedef unsigned short bf16_t;
typedef short bh8 __attribute__((ext_vector_type(8)));
typedef unsigned short us8 __attribute__((ext_vector_type(8)));
typedef float f32x4 __attribute__((ext_vector_type(4)));

__device__ __forceinline__ float bf2f(bf16_t x) {
    return __uint_as_float((unsigned)x << 16);
}
__device__ __forceinline__ bf16_t f2bf(float v) {
    unsigned u = __float_as_uint(v);
    return (bf16_t)((u + 0x7FFFu + ((u >> 16) & 1u)) >> 16);  // RNE
}
__device__ __forceinline__ ushort2 pk_f2bf(float a, float b) {
    __hip_bfloat162 h2 = __float22bfloat162_rn(float2{a, b});  // v_cvt_pk_bf16_f32
    union { __hip_bfloat162 h; ushort2 u; } u;
    u.h = h2;
    return u.u;
}

// ---------------- fused histogram + weight conversion (R15/R16-verified) ----------------

__global__ void hist_and_convert(
    const int* __restrict__ dst, int E, int eblocks, int* __restrict__ deg,
    const float* __restrict__ w0, const float* __restrict__ w1, const float* __restrict__ w2,
    const float* __restrict__ w3, const float* __restrict__ w4,
    const float* __restrict__ w5, const float* __restrict__ w6,
    const float* __restrict__ wr2, const float* __restrict__ br2,
    bf16_t* __restrict__ t0, bf16_t* __restrict__ t1, bf16_t* __restrict__ t2,
    bf16_t* __restrict__ t3, bf16_t* __restrict__ t4,
    bf16_t* __restrict__ t5, bf16_t* __restrict__ t6,
    bf16_t* __restrict__ teff, float* __restrict__ b_eff)
{
    int t = threadIdx.x;
    if ((int)blockIdx.x < eblocks) {
        int e = blockIdx.x * 256 + t;
        if (e < E) atomicAdd(&deg[dst[e]], 1);
        return;
    }
    int b = blockIdx.x - eblocks;
    const float* W; bf16_t* T; int K, Nc, lb;
    if (b < 384) {
        int g = b / 128; lb = b - g * 128;
        W = g == 0 ? w0 : (g == 1 ? w1 : w2);
        T = g == 0 ? t0 : (g == 1 ? t1 : t2);
        K = 128; Nc = 256;
    } else if (b < 896) {
        int g = (b - 384) / 256; lb = (b - 384) - g * 256;
        W = g == 0 ? w3 : w4; T = g == 0 ? t3 : t4;
        K = 256; Nc = 256;
    } else if (b < 1280) {
        int g = (b - 896) / 192; lb = (b - 896) - g * 192;
        W = g == 0 ? w5 : w6; T = g == 0 ? t5 : t6;
        K = 256; Nc = 160;
    } else {
        lb = b - 1280;
        int idx = lb * 256 + t;          // 64*256 = 16384 elems
        int n = idx >> 8, k = idx & 255;
        float v = 0.f;
        if (n < 40)
            v = 0.25f * (wr2[(size_t)k * 160 + n] + wr2[(size_t)k * 160 + 40 + n] +
                         wr2[(size_t)k * 160 + 80 + n] + wr2[(size_t)k * 160 + 120 + n]);
        teff[idx] = f2bf(v);
        if (lb == 0 && t < 40)
            b_eff[t] = 0.25f * (br2[t] + br2[40 + t] + br2[80 + t] + br2[120 + t]);
        return;
    }
    int idx = lb * 256 + t;
    int n = idx / K, k = idx - n * K;
    float v = (n < Nc) ? W[(size_t)k * Nc + n] : 0.f;
    T[idx] = f2bf(v);
}

// ---------------- CSR scan + degree-bucket sort ----------------
// deg_chunk_sum additionally builds a 128-bucket degree histogram (LDS-staged).

__global__ void deg_chunk_sum(const int* __restrict__ deg, int n,
                              int* __restrict__ chunk_sums, int* __restrict__ bcnt) {
    __shared__ int sm[256];
    __shared__ int hl[128];
    int t = threadIdx.x;
    if (t < 128) hl[t] = 0;
    __syncthreads();
    int base = blockIdx.x * 1024;
    int s = 0;
    for (int i = t; i < 1024; i += 256) {
        int idx = base + i;
        if (idx < n) {
            int d = deg[idx];
            s += d;
            atomicAdd(&hl[d < 127 ? d : 127], 1);
        }
    }
    sm[t] = s;
    __syncthreads();
    for (int off = 128; off > 0; off >>= 1) {
        if (t < off) sm[t] += sm[t + off];
        __syncthreads();
    }
    if (t == 0) chunk_sums[blockIdx.x] = sm[0];
    if (t < 128 && hl[t]) atomicAdd(&bcnt[t], hl[t]);
}

// scan_write: row_start prefix (as before) + degree-sorted node permutation.
// Counting sort: per-block LDS rank within bucket, one global atomic per
// bucket per block, then scatter perm[sbase[b]+gbase[b]+rank] = node.
__global__ void scan_write(const int* __restrict__ deg, int n,
                           const int* __restrict__ chunk_sums,
                           int* __restrict__ row_start, int Etot,
                           const int* __restrict__ bcnt, int* __restrict__ bfill,
                           int* __restrict__ perm) {
    __shared__ int sm[256];
    __shared__ int s_pref;
    __shared__ int sbase[128];
    __shared__ int lcnt[128];
    __shared__ int gbase[128];
    int base = blockIdx.x * 1024;
    int t = threadIdx.x;

    if (t < 128) lcnt[t] = 0;

    // wave 0: sum chunk_sums[0..blockIdx.x) via wave-reduce
    if (t < 64) {
        int v = (t < (int)blockIdx.x) ? chunk_sums[t] : 0;
#pragma unroll
        for (int off = 32; off > 0; off >>= 1)
            v += __shfl_down(v, off, 64);
        if (t == 0) s_pref = v;
    }
    // thread 128: serial exclusive prefix of the 128-bucket histogram
    if (t == 128) {
        int run = 0;
        for (int i = 0; i < 128; i++) { sbase[i] = run; run += bcnt[i]; }
    }

    int vv[4];
    int tsum = 0;
#pragma unroll
    for (int j = 0; j < 4; j++) {
        int idx = base + t * 4 + j;
        vv[j] = (idx < n) ? deg[idx] : 0;
        tsum += vv[j];
    }
    sm[t] = tsum;
    __syncthreads();
    for (int off = 1; off < 256; off <<= 1) {
        int x = (t >= off) ? sm[t - off] : 0;
        __syncthreads();
        sm[t] += x;
        __syncthreads();
    }
    int excl = sm[t] - tsum + s_pref;
#pragma unroll
    for (int j = 0; j < 4; j++) {
        int idx = base + t * 4 + j;
        if (idx < n) row_start[idx] = excl;
        excl += vv[j];
    }
    if (blockIdx.x == 0 && t == 0) row_start[n] = Etot;

    // ---- degree-bucket scatter ----
    int rnk[4], bb[4];
#pragma unroll
    for (int j = 0; j < 4; j++) {
        int idx = base + t * 4 + j;
        if (idx < n) {
            bb[j] = vv[j] < 127 ? vv[j] : 127;
            rnk[j] = atomicAdd(&lcnt[bb[j]], 1);
        } else bb[j] = -1;
    }
    __syncthreads();
    if (t < 128 && lcnt[t]) gbase[t] = atomicAdd(&bfill[t], lcnt[t]);
    __syncthreads();
#pragma unroll
    for (int j = 0; j < 4; j++) {
        int idx = base + t * 4 + j;
        if (bb[j] >= 0)
            perm[sbase[bb[j]] + gbase[bb[j]] + rnk[j]] = idx;
    }
}

// ---------------- single-A-stage multi-output MFMA GEMM (R14/R17 config) ----------------
// DO_SCATTER: blocks [mtiles, mtiles+eblocks) run the edge scatter (independent
// work overlapped with the layer-0 GEMM in one dispatch) and return early.

template <typename TA, int NOUT, int KTOT, int NPAD, bool SPLIT40, bool HAS_EFF, bool DO_SCATTER>
__global__ __launch_bounds__(256) void gemm_lds(
    const TA* __restrict__ A,
    const bf16_t* __restrict__ Wt0, const bf16_t* __restrict__ Wt1, const bf16_t* __restrict__ Wt2,
    const float* __restrict__ bias0, const float* __restrict__ bias1, const float* __restrict__ bias2,
    bf16_t* __restrict__ C0, bf16_t* __restrict__ C1, bf16_t* __restrict__ C2,
    const bf16_t* __restrict__ Wte, const float* __restrict__ biase, float* __restrict__ Ce,
    int M, int Nc,
    const int* __restrict__ e_dst, const int* __restrict__ e_src, int E,
    const int* __restrict__ row_start, int* __restrict__ fill,
    int* __restrict__ src_sorted, int mtiles)
{
    constexpr int LSTR = KTOT + 8;     // stage row stride
    constexpr int ESTR = 38;           // epilogue row stride
    constexpr int KC = KTOT / 32;
    __shared__ bf16_t As[64 * LSTR];
    __shared__ bf16_t Ep[4 * 64 * ESTR];

    int tid = threadIdx.x;

    if (DO_SCATTER && (int)blockIdx.x >= mtiles) {
        int e = (blockIdx.x - mtiles) * 256 + tid;
        if (e < E) {
            int d_ = e_dst[e];
            int pos = row_start[d_] + atomicAdd(&fill[d_], 1);
            src_sorted[pos] = e_src[e];
        }
        return;
    }

    int lane = tid & 63, w = tid >> 6;
    int lm = lane & 15, lq = lane >> 4;
    int m0 = blockIdx.x * 64;

    const bf16_t* Wts[3] = {Wt0, Wt1, Wt2};
    const float* biases[3] = {bias0, bias1, bias2};
    bf16_t* Cs[3] = {C0, C1, C2};

    // ---- stage A slab (64 rows x KTOT) once ----
    if (sizeof(TA) == 4) {            // KTOT == 128, f32 input
#pragma unroll
        for (int it = 0; it < 4; it++) {
            int idx = tid + it * 256;  // 1024 chunks of 8 floats
            int r = idx >> 4, c = idx & 15;
            int gm = m0 + r; if (gm >= M) gm = M - 1;
            const float* ap = (const float*)A + (size_t)gm * KTOT + c * 8;
            float4 lo = *(const float4*)ap;
            float4 hi = *(const float4*)(ap + 4);
            ushort2 p0 = pk_f2bf(lo.x, lo.y), p1 = pk_f2bf(lo.z, lo.w);
            ushort2 p2 = pk_f2bf(hi.x, hi.y), p3 = pk_f2bf(hi.z, hi.w);
            bh8 v = { (short)p0.x, (short)p0.y, (short)p1.x, (short)p1.y,
                      (short)p2.x, (short)p2.y, (short)p3.x, (short)p3.y };
            *(bh8*)(As + r * LSTR + c * 8) = v;
        }
    } else {                           // KTOT == 256, bf16 input
#pragma unroll
        for (int it = 0; it < 8; it++) {
            int idx = tid + it * 256;  // 2048 chunks of 8 bf16
            int r = idx >> 5, c = idx & 31;
            int gm = m0 + r; if (gm >= M) gm = M - 1;
            bh8 v = *(const bh8*)((const bf16_t*)A + (size_t)gm * KTOT + c * 8);
            *(bh8*)(As + r * LSTR + c * 8) = v;
        }
    }
    __syncthreads();   // the ONLY barrier

    bf16_t* ep = Ep + w * (64 * ESTR);
    constexpr int NCHUNK = (NPAD + 127) / 128;

#pragma unroll
    for (int chunk = 0; chunk < NCHUNK; chunk++) {
        int n0 = chunk * 128 + w * 32;
        if (n0 >= NPAD) continue;      // no barriers inside -> safe

        int boff[NOUT][2];
#pragma unroll
        for (int o = 0; o < NOUT; o++)
#pragma unroll
            for (int nt = 0; nt < 2; nt++)
                boff[o][nt] = (n0 + nt * 16 + lm) * KTOT + lq * 8;

        f32x4 acc[NOUT][4][2];
#pragma unroll
        for (int o = 0; o < NOUT; o++)
#pragma unroll
            for (int i = 0; i < 4; i++)
#pragma unroll
                for (int j = 0; j < 2; j++)
                    acc[o][i][j] = (f32x4){0.f, 0.f, 0.f, 0.f};

        bh8 bf_cur[NOUT][2], bf_nxt[NOUT][2];
#pragma unroll
        for (int o = 0; o < NOUT; o++)
#pragma unroll
            for (int nt = 0; nt < 2; nt++)
                bf_cur[o][nt] = *(const bh8*)(Wts[o] + boff[o][nt]);

#pragma unroll
        for (int kc = 0; kc < KC; kc++) {
            if (kc + 1 < KC) {
#pragma unroll
                for (int o = 0; o < NOUT; o++)
#pragma unroll
                    for (int nt = 0; nt < 2; nt++)
                        bf_nxt[o][nt] = *(const bh8*)(Wts[o] + boff[o][nt] + (kc + 1) * 32);
            }
            bh8 af[4];
#pragma unroll
            for (int mt = 0; mt < 4; mt++)
                af[mt] = *(const bh8*)(As + (mt * 16 + lm) * LSTR + kc * 32 + lq * 8);
#pragma unroll
            for (int o = 0; o < NOUT; o++)
#pragma unroll
                for (int mt = 0; mt < 4; mt++)
#pragma unroll
                    for (int nt = 0; nt < 2; nt++)
                        acc[o][mt][nt] = __builtin_amdgcn_mfma_f32_16x16x32_bf16(af[mt], bf_cur[o][nt], acc[o][mt][nt], 0, 0, 0);
            if (kc + 1 < KC) {
#pragma unroll
                for (int o = 0; o < NOUT; o++)
#pragma unroll
                    for (int nt = 0; nt < 2; nt++)
                        bf_cur[o][nt] = bf_nxt[o][nt];
            }
        }

        // ---- per-wave epilogue: private LDS tile -> full-line global stores ----
#pragma unroll
        for (int o = 0; o < NOUT; o++) {
#pragma unroll
            for (int nt = 0; nt < 2; nt++) {
                int gn = n0 + nt * 16 + lm;
                float bv = (gn < Nc) ? biases[o][gn] : 0.f;
#pragma unroll
                for (int mt = 0; mt < 4; mt++)
#pragma unroll
                    for (int r = 0; r < 4; r++)
                        ep[(mt * 16 + lq * 4 + r) * ESTR + nt * 16 + lm] = f2bf(acc[o][mt][nt][r] + bv);
            }
#pragma unroll
            for (int it = 0; it < 4; it++) {
                int row = it * 16 + (lane >> 2);
                int cc = (lane & 3) * 8;
                bh8 v = *(const bh8*)(ep + row * ESTR + cc);
                int gm = m0 + row;
                int cg = n0 + cc;
                if (gm < M && cg < Nc) {
                    size_t cb = SPLIT40 ? (size_t)(cg + 24 * (cg / 40)) : (size_t)cg;
                    size_t rs = SPLIT40 ? 256 : (size_t)Nc;
                    *(bh8*)(Cs[o] + (size_t)gm * rs + cb) = v;
                }
            }
        }
    }

    // ---- folded-residual pass (waves 0-1), reuses LDS A ----
    if (HAS_EFF && w < 2) {
        int beoff[2];
#pragma unroll
        for (int nt = 0; nt < 2; nt++)
            beoff[nt] = (w * 32 + nt * 16 + lm) * KTOT + lq * 8;
        f32x4 acc_e[4][2];
#pragma unroll
        for (int i = 0; i < 4; i++)
#pragma unroll
            for (int j = 0; j < 2; j++)
                acc_e[i][j] = (f32x4){0.f, 0.f, 0.f, 0.f};
#pragma unroll
        for (int kc = 0; kc < KC; kc++) {
            bh8 af[4];
#pragma unroll
            for (int mt = 0; mt < 4; mt++)
                af[mt] = *(const bh8*)(As + (mt * 16 + lm) * LSTR + kc * 32 + lq * 8);
            bh8 be[2];
#pragma unroll
            for (int nt = 0; nt < 2; nt++)
                be[nt] = *(const bh8*)(Wte + beoff[nt] + kc * 32);
#pragma unroll
            for (int mt = 0; mt < 4; mt++)
#pragma unroll
                for (int nt = 0; nt < 2; nt++)
                    acc_e[mt][nt] = __builtin_amdgcn_mfma_f32_16x16x32_bf16(af[mt], be[nt], acc_e[mt][nt], 0, 0, 0);
        }
#pragma unroll
        for (int nt = 0; nt < 2; nt++) {
            int gn = w * 32 + nt * 16 + lm;
            if (gn >= 40) continue;
            float bv = biase[gn];
#pragma unroll
            for (int mt = 0; mt < 4; mt++)
#pragma unroll
                for (int r = 0; r < 4; r++) {
                    int gm = m0 + mt * 16 + lq * 4 + r;
                    if (gm < M) Ce[(size_t)gm * 40 + gn] = acc_e[mt][nt][r] + bv;
                }
        }
    }
}

// ---------------- GATv2 aggregation: QUARTER-WAVE per node, 2-edge pipeline ----------------
// R16 post-mortem: __launch_bounds__(256,4) makes the allocator target 64 VGPR
// -> ~26 regs of spill (WRITE_SIZE 108MB scratch). Fix: plain
// __launch_bounds__(256); compiler allocates the natural ~90-110 VGPR,
// no spill, ~5 waves/SIMD. Keeps LPT order + 2-edge prefetch +
// on-the-fly bf16 conversion + index prefetch.

__device__ __forceinline__ void us8_to_f(const us8 v, float* h) {
#pragma unroll
    for (int j = 0; j < 8; j++) h[j] = bf2f(v[j]);
}

template <int DVALID, bool FINAL, bool RES_INPLACE>
__global__ __launch_bounds__(256) void gat_agg_quarter(
    const bf16_t* __restrict__ hs, const bf16_t* __restrict__ hd,
    const float* __restrict__ attn,
    const int* __restrict__ row_start, const int* __restrict__ src_sorted,
    const int* __restrict__ perm,
    bf16_t* __restrict__ P, float* __restrict__ out_final, int N)
{
    int w = threadIdx.x >> 6, lane = threadIdx.x & 63;
    int q = lane >> 4, ql = lane & 15;
    int gq = blockIdx.x * 16 + w * 4 + q;
    if (gq >= N) return;
    int n = perm[(N - 1) - gq];   // descending degree: LPT scheduling
    int f0 = ql * 16;         // padded feature base
    int h = ql >> 2;          // head
    int dp = (ql & 3) * 16;   // d within head (padded)

    float at[16], hdf[16];
#pragma unroll
    for (int j = 0; j < 16; j++)
        at[j] = (dp + j < DVALID) ? attn[h * DVALID + dp + j] : 0.f;
    {
        us8 a = *(const us8*)(hd + (unsigned)(n * 256 + f0));
        us8 b = *(const us8*)(hd + (unsigned)(n * 256 + f0 + 8));
        us8_to_f(a, hdf); us8_to_f(b, hdf + 8);
    }

    // per-node proxy center: logit at hs=0 (keeps exp args small; logits bounded)
    float pc;
    {
        float p = 0.f;
#pragma unroll
        for (int j = 0; j < 16; j++) {
            float qq = hdf[j];
            p += fmaxf(qq, SLOPE * qq) * at[j];
        }
        p += __shfl_xor(p, 1, 64);
        p += __shfl_xor(p, 2, 64);
        pc = p;
    }

    int s = row_start[n], e = row_start[n + 1];

    float cl = 0.f;
    float ca[16] = {};

    // process one gathered row (two us8) into (cl, ca); conversion on the fly
    auto proc = [&](const us8 ra, const us8 rb) {
        float p = 0.f;
#pragma unroll
        for (int j = 0; j < 8; j++) {
            float qa = bf2f(ra[j]) + hdf[j];
            p += fmaxf(qa, SLOPE * qa) * at[j];
            float qb = bf2f(rb[j]) + hdf[8 + j];
            p += fmaxf(qb, SLOPE * qb) * at[8 + j];
        }
        p += __shfl_xor(p, 1, 64);
        p += __shfl_xor(p, 2, 64);
        float wk = __expf(p - pc);
        cl += wk;
#pragma unroll
        for (int j = 0; j < 8; j++) {
            ca[j]     += wk * bf2f(ra[j]);
            ca[8 + j] += wk * bf2f(rb[j]);
        }
    };

#define GA(sn) (*(const us8*)(hs + (unsigned)((sn) * 256 + f0)))
#define GB(sn) (*(const us8*)(hs + (unsigned)((sn) * 256 + f0 + 8)))

    int i = s;
    if (i + 4 <= e) {
        int a0 = src_sorted[i], a1 = src_sorted[i + 1];
        us8 c0a = GA(a0), c0b = GB(a0), c1a = GA(a1), c1b = GB(a1);
        int b0 = src_sorted[i + 2], b1 = src_sorted[i + 3];

        for (; i + 4 <= e; i += 2) {
            // issue next pair's 4 gathers before current pair's VALU
            us8 n0a = GA(b0), n0b = GB(b0), n1a = GA(b1), n1b = GB(b1);
            // prefetch indices one stage further ahead
            if (i + 6 <= e) { b0 = src_sorted[i + 4]; b1 = src_sorted[i + 5]; }
            proc(c0a, c0b); proc(c1a, c1b);
            c0a = n0a; c0b = n0b; c1a = n1a; c1b = n1b;
        }
        // drain current pair
        proc(c0a, c0b); proc(c1a, c1b);
        i += 2;
    }
    // remainder (< 4 edges total, or <= 1 tail after pipeline)
    for (; i + 2 <= e; i += 2) {
        int a0 = src_sorted[i], a1 = src_sorted[i + 1];
        us8 r0a = GA(a0), r0b = GB(a0), r1a = GA(a1), r1b = GB(a1);
        proc(r0a, r0b); proc(r1a, r1b);
    }
    if (i < e) {
        int a0 = src_sorted[i];
        us8 r0a = GA(a0), r0b = GB(a0);
        proc(r0a, r0b);
    }
#undef GA
#undef GB

    float v[16] = {};
    if (e > s) {
        float inv = 1.f / cl;
#pragma unroll
        for (int j = 0; j < 16; j++)
            v[j] = ca[j] * inv;
    }

    if (FINAL) {
        // head-sum: lanes ql, ql^4, ql^8, ql^12 hold the same d-range across heads
#pragma unroll
        for (int j = 0; j < 16; j++) {
            v[j] += __shfl_xor(v[j], 4, 64);
            v[j] += __shfl_xor(v[j], 8, 64);
        }
        if (h == 0) {
#pragma unroll
            for (int jj = 0; jj < 16; jj += 4) {
                if (dp + jj < DVALID) {   // DVALID % 4 == 0 -> whole float4 valid
                    float* op = out_final + (unsigned)(n * DVALID + dp + jj);
                    float4 cur = *(float4*)op;
                    cur.x += 0.25f * v[jj];
                    cur.y += 0.25f * v[jj + 1];
                    cur.z += 0.25f * v[jj + 2];
                    cur.w += 0.25f * v[jj + 3];
                    *(float4*)op = cur;
                }
            }
        }
    } else {
        unsigned oi = (unsigned)(n * 256 + f0);
        if (RES_INPLACE) {
            us8 pa = *(const us8*)(P + oi);
            us8 pb = *(const us8*)(P + oi + 8);
#pragma unroll
            for (int j = 0; j < 8; j++) {
                v[j] += bf2f(pa[j]);
                v[8 + j] += bf2f(pb[j]);
            }
        }
        us8 oa, ob;
#pragma unroll
        for (int j = 0; j < 8; j++) {
            oa[j] = f2bf(v[j]);
            ob[j] = f2bf(v[8 + j]);
        }
        *(us8*)(P + oi) = oa;
        *(us8*)(P + oi + 8) = ob;
    }
}

// ---------------- launch ----------------

extern "C" void kernel_launch(void* const* d_in, const int* in_sizes, int n_in,
                              void* d_out, int out_size, void* d_ws, size_t ws_size,
                              hipStream_t stream) {
    const float* x0    = (const float*)d_in[0];
    const int*   src   = (const int*)d_in[1];
    const int*   dst   = (const int*)d_in[2];
    const float* w_src0 = (const float*)d_in[3];  const float* b_src0 = (const float*)d_in[4];
    const float* w_dst0 = (const float*)d_in[5];  const float* b_dst0 = (const float*)d_in[6];
    const float* attn0  = (const float*)d_in[7];
    const float* w_res0 = (const float*)d_in[8];  const float* b_res0 = (const float*)d_in[9];
    const float* w_src1 = (const float*)d_in[10]; const float* b_src1 = (const float*)d_in[11];
    const float* w_dst1 = (const float*)d_in[12]; const float* b_dst1 = (const float*)d_in[13];
    const float* attn1  = (const float*)d_in[14];
    const float* w_src2 = (const float*)d_in[15]; const float* b_src2 = (const float*)d_in[16];
    const float* w_dst2 = (const float*)d_in[17]; const float* b_dst2 = (const float*)d_in[18];
    const float* attn2  = (const float*)d_in[19];
    const float* w_res2 = (const float*)d_in[20]; const float* b_res2 = (const float*)d_in[21];

    const int N = in_sizes[0] / 128;   // 50000
    const int E = in_sizes[1];         // 400000
    float* out = (float*)d_out;
    (void)n_in; (void)out_size; (void)ws_size;

    // ---- workspace (~80 MB) ----
    char* ws = (char*)d_ws;
    size_t off = 0;
    auto alloc = [&](size_t bytes) {
        void* q = ws + off;
        off = (off + bytes + 255) & ~(size_t)255;
        return q;
    };
    int* deg        = (int*)alloc((size_t)2 * N * 4);
    int* fill       = deg + N;
    int* bcnt       = (int*)alloc(256 * 4);     // 128 bucket counts + 128 fill
    int* bfill      = bcnt + 128;
    int* perm       = (int*)alloc((size_t)N * 4);
    int* row_start  = (int*)alloc((size_t)(N + 1) * 4);
    int* chunk_sums = (int*)alloc(256 * 4);
    int* src_sorted = (int*)alloc((size_t)E * 4);
    bf16_t* t_src0 = (bf16_t*)alloc(256 * 128 * 2);
    bf16_t* t_dst0 = (bf16_t*)alloc(256 * 128 * 2);
    bf16_t* t_res0 = (bf16_t*)alloc(256 * 128 * 2);
    bf16_t* t_src1 = (bf16_t*)alloc(256 * 256 * 2);
    bf16_t* t_dst1 = (bf16_t*)alloc(256 * 256 * 2);
    bf16_t* t_src2 = (bf16_t*)alloc(192 * 256 * 2);
    bf16_t* t_dst2 = (bf16_t*)alloc(192 * 256 * 2);
    bf16_t* t_eff  = (bf16_t*)alloc(64 * 256 * 2);
    float*  b_eff  = (float*)alloc(64 * 4);
    const size_t elems = (size_t)N * 256;
    bf16_t* P  = (bf16_t*)alloc(elems * 2);
    bf16_t* HS = (bf16_t*)alloc(elems * 2);
    bf16_t* HD = (bf16_t*)alloc(elems * 2);

    // ---- CSR build + degree sort + weight conversion ----
    hipMemsetAsync(deg, 0, (size_t)2 * N * 4, stream);
    hipMemsetAsync(bcnt, 0, 256 * 4, stream);
    int eblocks = (E + 255) / 256;     // 1563
    int nchunks = (N + 1023) / 1024;   // 49 (<= 64 required by scan_write)
    hipLaunchKernelGGL(hist_and_convert, dim3(eblocks + 1344), dim3(256), 0, stream,
                       dst, E, eblocks, deg,
                       w_src0, w_dst0, w_res0, w_src1, w_dst1, w_src2, w_dst2, w_res2, b_res2,
                       t_src0, t_dst0, t_res0, t_src1, t_dst1, t_src2, t_dst2, t_eff, b_eff);
    hipLaunchKernelGGL(deg_chunk_sum, dim3(nchunks), dim3(256), 0, stream, deg, N, chunk_sums, bcnt);
    hipLaunchKernelGGL(scan_write, dim3(nchunks), dim3(256), 0, stream, deg, N, chunk_sums,
                       row_start, E, bcnt, bfill, perm);

    dim3 blk(256);
    int mtiles = (N + 63) / 64;        // 782
    int ab = (N + 15) / 16;            // 3125 (quarter-wave-per-node agg)

    // ---- Layer 0: fused hs|hd|res GEMM from x0, OVERLAPPED with edge scatter ----
    hipLaunchKernelGGL((gemm_lds<float, 3, 128, 256, false, false, true>),
                       dim3(mtiles + eblocks), blk, 0, stream,
                       x0, t_src0, t_dst0, t_res0, b_src0, b_dst0, b_res0,
                       HS, HD, P,
                       (const bf16_t*)nullptr, (const float*)nullptr, (float*)nullptr,
                       N, 256,
                       dst, src, E, row_start, fill, src_sorted, mtiles);
    hipLaunchKernelGGL((gat_agg_quarter<64, false, true>), dim3(ab), blk, 0, stream,
                       HS, HD, attn0, row_start, src_sorted, perm, P, (float*)nullptr, N);

    // ---- Layer 1: fused hs|hd from P; identity residual in-place ----
    hipLaunchKernelGGL((gemm_lds<bf16_t, 2, 256, 256, false, false, false>), dim3(mtiles), blk, 0, stream,
                       P, t_src1, t_dst1, (const bf16_t*)nullptr, b_src1, b_dst1, (const float*)nullptr,
                       HS, HD, (bf16_t*)nullptr,
                       (const bf16_t*)nullptr, (const float*)nullptr, (float*)nullptr,
                       N, 256,
                       (const int*)nullptr, (const int*)nullptr, 0,
                       (const int*)nullptr, (int*)nullptr, (int*)nullptr, 0);
    hipLaunchKernelGGL((gat_agg_quarter<64, false, true>), dim3(ab), blk, 0, stream,
                       HS, HD, attn1, row_start, src_sorted, perm, P, (float*)nullptr, N);

    // ---- Layer 2: fused hs|hd (SPLIT40) + eff residual (f32 -> out); FINAL agg accumulates ----
    hipLaunchKernelGGL((gemm_lds<bf16_t, 2, 256, 192, true, true, false>), dim3(mtiles), blk, 0, stream,
                       P, t_src2, t_dst2, (const bf16_t*)nullptr, b_src2, b_dst2, (const float*)nullptr,
                       HS, HD, (bf16_t*)nullptr,
                       t_eff, b_eff, out,
                       N, 160,
                       (const int*)nullptr, (const int*)nullptr, 0,
                       (const int*)nullptr, (int*)nullptr, (int*)nullptr, 0);
    hipLaunchKernelGGL((gat_agg_quarter<40, true, false>), dim3(ab), blk, 0, stream,
                       HS, HD, attn2, row_start, src_sorted, perm, (bf16_t*)nullptr, out, N);
}

// Round 20
// 401.000 us; speedup vs baseline: 1.4891x; 1.0020x over previous
//
#include <hip/hip_runtime.h>
#include <hip/hip_bf16.h>
#include <math.h>

// N=50000, E=400000, F_IN=128, HID=64, OUT=40, H=4
#define SLOPE 0.2f

typedef unsigned short bf16_t;
typedef short bh8 __attribute__((ext_vector_type(8)));
typedef unsigned short us8 __attribute__((ext_vector_type(8)));
typedef float f32x4 __attribute__((ext_vector_type(4)));

__device__ __forceinline__ float bf2f(bf16_t x) {
    return __uint_as_float((unsigned)x << 16);
}
__device__ __forceinline__ bf16_t f2bf(float v) {
    unsigned u = __float_as_uint(v);
    return (bf16_t)((u + 0x7FFFu + ((u >> 16) & 1u)) >> 16);  // RNE
}
__device__ __forceinline__ ushort2 pk_f2bf(float a, float b) {
    __hip_bfloat162 h2 = __float22bfloat162_rn(float2{a, b});  // v_cvt_pk_bf16_f32
    union { __hip_bfloat162 h; ushort2 u; } u;
    u.h = h2;
    return u.u;
}

// ---------------- fused histogram + weight conversion (R15/R16-verified) ----------------

__global__ void hist_and_convert(
    const int* __restrict__ dst, int E, int eblocks, int* __restrict__ deg,
    const float* __restrict__ w0, const float* __restrict__ w1, const float* __restrict__ w2,
    const float* __restrict__ w3, const float* __restrict__ w4,
    const float* __restrict__ w5, const float* __restrict__ w6,
    const float* __restrict__ wr2, const float* __restrict__ br2,
    bf16_t* __restrict__ t0, bf16_t* __restrict__ t1, bf16_t* __restrict__ t2,
    bf16_t* __restrict__ t3, bf16_t* __restrict__ t4,
    bf16_t* __restrict__ t5, bf16_t* __restrict__ t6,
    bf16_t* __restrict__ teff, float* __restrict__ b_eff)
{
    int t = threadIdx.x;
    if ((int)blockIdx.x < eblocks) {
        int e = blockIdx.x * 256 + t;
        if (e < E) atomicAdd(&deg[dst[e]], 1);
        return;
    }
    int b = blockIdx.x - eblocks;
    const float* W; bf16_t* T; int K, Nc, lb;
    if (b < 384) {
        int g = b / 128; lb = b - g * 128;
        W = g == 0 ? w0 : (g == 1 ? w1 : w2);
        T = g == 0 ? t0 : (g == 1 ? t1 : t2);
        K = 128; Nc = 256;
    } else if (b < 896) {
        int g = (b - 384) / 256; lb = (b - 384) - g * 256;
        W = g == 0 ? w3 : w4; T = g == 0 ? t3 : t4;
        K = 256; Nc = 256;
    } else if (b < 1280) {
        int g = (b - 896) / 192; lb = (b - 896) - g * 192;
        W = g == 0 ? w5 : w6; T = g == 0 ? t5 : t6;
        K = 256; Nc = 160;
    } else {
        lb = b - 1280;
        int idx = lb * 256 + t;          // 64*256 = 16384 elems
        int n = idx >> 8, k = idx & 255;
        float v = 0.f;
        if (n < 40)
            v = 0.25f * (wr2[(size_t)k * 160 + n] + wr2[(size_t)k * 160 + 40 + n] +
                         wr2[(size_t)k * 160 + 80 + n] + wr2[(size_t)k * 160 + 120 + n]);
        teff[idx] = f2bf(v);
        if (lb == 0 && t < 40)
            b_eff[t] = 0.25f * (br2[t] + br2[40 + t] + br2[80 + t] + br2[120 + t]);
        return;
    }
    int idx = lb * 256 + t;
    int n = idx / K, k = idx - n * K;
    float v = (n < Nc) ? W[(size_t)k * Nc + n] : 0.f;
    T[idx] = f2bf(v);
}

// ---------------- CSR scan + degree-bucket sort ----------------
// deg_chunk_sum additionally builds a 128-bucket degree histogram (LDS-staged).

__global__ void deg_chunk_sum(const int* __restrict__ deg, int n,
                              int* __restrict__ chunk_sums, int* __restrict__ bcnt) {
    __shared__ int sm[256];
    __shared__ int hl[128];
    int t = threadIdx.x;
    if (t < 128) hl[t] = 0;
    __syncthreads();
    int base = blockIdx.x * 1024;
    int s = 0;
    for (int i = t; i < 1024; i += 256) {
        int idx = base + i;
        if (idx < n) {
            int d = deg[idx];
            s += d;
            atomicAdd(&hl[d < 127 ? d : 127], 1);
        }
    }
    sm[t] = s;
    __syncthreads();
    for (int off = 128; off > 0; off >>= 1) {
        if (t < off) sm[t] += sm[t + off];
        __syncthreads();
    }
    if (t == 0) chunk_sums[blockIdx.x] = sm[0];
    if (t < 128 && hl[t]) atomicAdd(&bcnt[t], hl[t]);
}

// scan_write: row_start prefix (as before) + degree-sorted node permutation.
// Counting sort: per-block LDS rank within bucket, one global atomic per
// bucket per block, then scatter perm[sbase[b]+gbase[b]+rank] = node.
__global__ void scan_write(const int* __restrict__ deg, int n,
                           const int* __restrict__ chunk_sums,
                           int* __restrict__ row_start, int Etot,
                           const int* __restrict__ bcnt, int* __restrict__ bfill,
                           int* __restrict__ perm) {
    __shared__ int sm[256];
    __shared__ int s_pref;
    __shared__ int sbase[128];
    __shared__ int lcnt[128];
    __shared__ int gbase[128];
    int base = blockIdx.x * 1024;
    int t = threadIdx.x;

    if (t < 128) lcnt[t] = 0;

    // wave 0: sum chunk_sums[0..blockIdx.x) via wave-reduce
    if (t < 64) {
        int v = (t < (int)blockIdx.x) ? chunk_sums[t] : 0;
#pragma unroll
        for (int off = 32; off > 0; off >>= 1)
            v += __shfl_down(v, off, 64);
        if (t == 0) s_pref = v;
    }
    // thread 128: serial exclusive prefix of the 128-bucket histogram
    if (t == 128) {
        int run = 0;
        for (int i = 0; i < 128; i++) { sbase[i] = run; run += bcnt[i]; }
    }

    int vv[4];
    int tsum = 0;
#pragma unroll
    for (int j = 0; j < 4; j++) {
        int idx = base + t * 4 + j;
        vv[j] = (idx < n) ? deg[idx] : 0;
        tsum += vv[j];
    }
    sm[t] = tsum;
    __syncthreads();
    for (int off = 1; off < 256; off <<= 1) {
        int x = (t >= off) ? sm[t - off] : 0;
        __syncthreads();
        sm[t] += x;
        __syncthreads();
    }
    int excl = sm[t] - tsum + s_pref;
#pragma unroll
    for (int j = 0; j < 4; j++) {
        int idx = base + t * 4 + j;
        if (idx < n) row_start[idx] = excl;
        excl += vv[j];
    }
    if (blockIdx.x == 0 && t == 0) row_start[n] = Etot;

    // ---- degree-bucket scatter ----
    int rnk[4], bb[4];
#pragma unroll
    for (int j = 0; j < 4; j++) {
        int idx = base + t * 4 + j;
        if (idx < n) {
            bb[j] = vv[j] < 127 ? vv[j] : 127;
            rnk[j] = atomicAdd(&lcnt[bb[j]], 1);
        } else bb[j] = -1;
    }
    __syncthreads();
    if (t < 128 && lcnt[t]) gbase[t] = atomicAdd(&bfill[t], lcnt[t]);
    __syncthreads();
#pragma unroll
    for (int j = 0; j < 4; j++) {
        int idx = base + t * 4 + j;
        if (bb[j] >= 0)
            perm[sbase[bb[j]] + gbase[bb[j]] + rnk[j]] = idx;
    }
}

// ---------------- single-A-stage multi-output MFMA GEMM (R14/R17 config) ----------------
// DO_SCATTER: blocks [mtiles, mtiles+eblocks) run the edge scatter (independent
// work overlapped with the layer-0 GEMM in one dispatch) and return early.

template <typename TA, int NOUT, int KTOT, int NPAD, bool SPLIT40, bool HAS_EFF, bool DO_SCATTER>
__global__ __launch_bounds__(256) void gemm_lds(
    const TA* __restrict__ A,
    const bf16_t* __restrict__ Wt0, const bf16_t* __restrict__ Wt1, const bf16_t* __restrict__ Wt2,
    const float* __restrict__ bias0, const float* __restrict__ bias1, const float* __restrict__ bias2,
    bf16_t* __restrict__ C0, bf16_t* __restrict__ C1, bf16_t* __restrict__ C2,
    const bf16_t* __restrict__ Wte, const float* __restrict__ biase, float* __restrict__ Ce,
    int M, int Nc,
    const int* __restrict__ e_dst, const int* __restrict__ e_src, int E,
    const int* __restrict__ row_start, int* __restrict__ fill,
    int* __restrict__ src_sorted, int mtiles)
{
    constexpr int LSTR = KTOT + 8;     // stage row stride
    constexpr int ESTR = 38;           // epilogue row stride
    constexpr int KC = KTOT / 32;
    __shared__ bf16_t As[64 * LSTR];
    __shared__ bf16_t Ep[4 * 64 * ESTR];

    int tid = threadIdx.x;

    if (DO_SCATTER && (int)blockIdx.x >= mtiles) {
        int e = (blockIdx.x - mtiles) * 256 + tid;
        if (e < E) {
            int d_ = e_dst[e];
            int pos = row_start[d_] + atomicAdd(&fill[d_], 1);
            src_sorted[pos] = e_src[e];
        }
        return;
    }

    int lane = tid & 63, w = tid >> 6;
    int lm = lane & 15, lq = lane >> 4;
    int m0 = blockIdx.x * 64;

    const bf16_t* Wts[3] = {Wt0, Wt1, Wt2};
    const float* biases[3] = {bias0, bias1, bias2};
    bf16_t* Cs[3] = {C0, C1, C2};

    // ---- stage A slab (64 rows x KTOT) once ----
    if (sizeof(TA) == 4) {            // KTOT == 128, f32 input
#pragma unroll
        for (int it = 0; it < 4; it++) {
            int idx = tid + it * 256;  // 1024 chunks of 8 floats
            int r = idx >> 4, c = idx & 15;
            int gm = m0 + r; if (gm >= M) gm = M - 1;
            const float* ap = (const float*)A + (size_t)gm * KTOT + c * 8;
            float4 lo = *(const float4*)ap;
            float4 hi = *(const float4*)(ap + 4);
            ushort2 p0 = pk_f2bf(lo.x, lo.y), p1 = pk_f2bf(lo.z, lo.w);
            ushort2 p2 = pk_f2bf(hi.x, hi.y), p3 = pk_f2bf(hi.z, hi.w);
            bh8 v = { (short)p0.x, (short)p0.y, (short)p1.x, (short)p1.y,
                      (short)p2.x, (short)p2.y, (short)p3.x, (short)p3.y };
            *(bh8*)(As + r * LSTR + c * 8) = v;
        }
    } else {                           // KTOT == 256, bf16 input
#pragma unroll
        for (int it = 0; it < 8; it++) {
            int idx = tid + it * 256;  // 2048 chunks of 8 bf16
            int r = idx >> 5, c = idx & 31;
            int gm = m0 + r; if (gm >= M) gm = M - 1;
            bh8 v = *(const bh8*)((const bf16_t*)A + (size_t)gm * KTOT + c * 8);
            *(bh8*)(As + r * LSTR + c * 8) = v;
        }
    }
    __syncthreads();   // the ONLY barrier

    bf16_t* ep = Ep + w * (64 * ESTR);
    constexpr int NCHUNK = (NPAD + 127) / 128;

#pragma unroll
    for (int chunk = 0; chunk < NCHUNK; chunk++) {
        int n0 = chunk * 128 + w * 32;
        if (n0 >= NPAD) continue;      // no barriers inside -> safe

        int boff[NOUT][2];
#pragma unroll
        for (int o = 0; o < NOUT; o++)
#pragma unroll
            for (int nt = 0; nt < 2; nt++)
                boff[o][nt] = (n0 + nt * 16 + lm) * KTOT + lq * 8;

        f32x4 acc[NOUT][4][2];
#pragma unroll
        for (int o = 0; o < NOUT; o++)
#pragma unroll
            for (int i = 0; i < 4; i++)
#pragma unroll
                for (int j = 0; j < 2; j++)
                    acc[o][i][j] = (f32x4){0.f, 0.f, 0.f, 0.f};

        bh8 bf_cur[NOUT][2], bf_nxt[NOUT][2];
#pragma unroll
        for (int o = 0; o < NOUT; o++)
#pragma unroll
            for (int nt = 0; nt < 2; nt++)
                bf_cur[o][nt] = *(const bh8*)(Wts[o] + boff[o][nt]);

#pragma unroll
        for (int kc = 0; kc < KC; kc++) {
            if (kc + 1 < KC) {
#pragma unroll
                for (int o = 0; o < NOUT; o++)
#pragma unroll
                    for (int nt = 0; nt < 2; nt++)
                        bf_nxt[o][nt] = *(const bh8*)(Wts[o] + boff[o][nt] + (kc + 1) * 32);
            }
            bh8 af[4];
#pragma unroll
            for (int mt = 0; mt < 4; mt++)
                af[mt] = *(const bh8*)(As + (mt * 16 + lm) * LSTR + kc * 32 + lq * 8);
#pragma unroll
            for (int o = 0; o < NOUT; o++)
#pragma unroll
                for (int mt = 0; mt < 4; mt++)
#pragma unroll
                    for (int nt = 0; nt < 2; nt++)
                        acc[o][mt][nt] = __builtin_amdgcn_mfma_f32_16x16x32_bf16(af[mt], bf_cur[o][nt], acc[o][mt][nt], 0, 0, 0);
            if (kc + 1 < KC) {
#pragma unroll
                for (int o = 0; o < NOUT; o++)
#pragma unroll
                    for (int nt = 0; nt < 2; nt++)
                        bf_cur[o][nt] = bf_nxt[o][nt];
            }
        }

        // ---- per-wave epilogue: private LDS tile -> full-line global stores ----
#pragma unroll
        for (int o = 0; o < NOUT; o++) {
#pragma unroll
            for (int nt = 0; nt < 2; nt++) {
                int gn = n0 + nt * 16 + lm;
                float bv = (gn < Nc) ? biases[o][gn] : 0.f;
#pragma unroll
                for (int mt = 0; mt < 4; mt++)
#pragma unroll
                    for (int r = 0; r < 4; r++)
                        ep[(mt * 16 + lq * 4 + r) * ESTR + nt * 16 + lm] = f2bf(acc[o][mt][nt][r] + bv);
            }
#pragma unroll
            for (int it = 0; it < 4; it++) {
                int row = it * 16 + (lane >> 2);
                int cc = (lane & 3) * 8;
                bh8 v = *(const bh8*)(ep + row * ESTR + cc);
                int gm = m0 + row;
                int cg = n0 + cc;
                if (gm < M && cg < Nc) {
                    size_t cb = SPLIT40 ? (size_t)(cg + 24 * (cg / 40)) : (size_t)cg;
                    size_t rs = SPLIT40 ? 256 : (size_t)Nc;
                    *(bh8*)(Cs[o] + (size_t)gm * rs + cb) = v;
                }
            }
        }
    }

    // ---- folded-residual pass (waves 0-1), reuses LDS A ----
    if (HAS_EFF && w < 2) {
        int beoff[2];
#pragma unroll
        for (int nt = 0; nt < 2; nt++)
            beoff[nt] = (w * 32 + nt * 16 + lm) * KTOT + lq * 8;
        f32x4 acc_e[4][2];
#pragma unroll
        for (int i = 0; i < 4; i++)
#pragma unroll
            for (int j = 0; j < 2; j++)
                acc_e[i][j] = (f32x4){0.f, 0.f, 0.f, 0.f};
#pragma unroll
        for (int kc = 0; kc < KC; kc++) {
            bh8 af[4];
#pragma unroll
            for (int mt = 0; mt < 4; mt++)
                af[mt] = *(const bh8*)(As + (mt * 16 + lm) * LSTR + kc * 32 + lq * 8);
            bh8 be[2];
#pragma unroll
            for (int nt = 0; nt < 2; nt++)
                be[nt] = *(const bh8*)(Wte + beoff[nt] + kc * 32);
#pragma unroll
            for (int mt = 0; mt < 4; mt++)
#pragma unroll
                for (int nt = 0; nt < 2; nt++)
                    acc_e[mt][nt] = __builtin_amdgcn_mfma_f32_16x16x32_bf16(af[mt], be[nt], acc_e[mt][nt], 0, 0, 0);
        }
#pragma unroll
        for (int nt = 0; nt < 2; nt++) {
            int gn = w * 32 + nt * 16 + lm;
            if (gn >= 40) continue;
            float bv = biase[gn];
#pragma unroll
            for (int mt = 0; mt < 4; mt++)
#pragma unroll
                for (int r = 0; r < 4; r++) {
                    int gm = m0 + mt * 16 + lq * 4 + r;
                    if (gm < M) Ce[(size_t)gm * 40 + gn] = acc_e[mt][nt][r] + bv;
                }
        }
    }
}

// ---------------- GATv2 aggregation: QUARTER-WAVE per node, 2-edge pipeline ----------------
// R17 config (401.8us verified): plain __launch_bounds__(256) (R16 lesson:
// the ",4" hint targets 64 VGPR and force-spills), LPT order, 2-edge
// prefetch, on-the-fly bf16 conversion, index prefetch.
// R18: DVALID-aware gather skip -- for the FINAL agg (DVALID=40), lanes
// whose 16-feature slice is past DVALID fetch zeros instead of loading
// (at[]=0 already nullifies their logit contribution; their v is never
// read). Removes 37.5% of final-agg gather bytes. For DVALID=64 the
// guards constant-fold away (identical codegen to R17).

__device__ __forceinline__ void us8_to_f(const us8 v, float* h) {
#pragma unroll
    for (int j = 0; j < 8; j++) h[j] = bf2f(v[j]);
}

template <int DVALID, bool FINAL, bool RES_INPLACE>
__global__ __launch_bounds__(256) void gat_agg_quarter(
    const bf16_t* __restrict__ hs, const bf16_t* __restrict__ hd,
    const float* __restrict__ attn,
    const int* __restrict__ row_start, const int* __restrict__ src_sorted,
    const int* __restrict__ perm,
    bf16_t* __restrict__ P, float* __restrict__ out_final, int N)
{
    int w = threadIdx.x >> 6, lane = threadIdx.x & 63;
    int q = lane >> 4, ql = lane & 15;
    int gq = blockIdx.x * 16 + w * 4 + q;
    if (gq >= N) return;
    int n = perm[(N - 1) - gq];   // descending degree: LPT scheduling
    int f0 = ql * 16;         // padded feature base
    int h = ql >> 2;          // head
    int dp = (ql & 3) * 16;   // d within head (padded)

    const bool vA = (dp < DVALID);       // first 8 dims of slice valid?
    const bool vB = (dp + 8 < DVALID);   // second 8 dims valid?

    float at[16], hdf[16];
#pragma unroll
    for (int j = 0; j < 16; j++)
        at[j] = (dp + j < DVALID) ? attn[h * DVALID + dp + j] : 0.f;
    {
        us8 z = {0, 0, 0, 0, 0, 0, 0, 0};
        us8 a = z, b = z;
        if (vA) a = *(const us8*)(hd + (unsigned)(n * 256 + f0));
        if (vB) b = *(const us8*)(hd + (unsigned)(n * 256 + f0 + 8));
        us8_to_f(a, hdf); us8_to_f(b, hdf + 8);
    }

    // per-node proxy center: logit at hs=0 (keeps exp args small; logits bounded)
    float pc;
    {
        float p = 0.f;
#pragma unroll
        for (int j = 0; j < 16; j++) {
            float qq = hdf[j];
            p += fmaxf(qq, SLOPE * qq) * at[j];
        }
        p += __shfl_xor(p, 1, 64);
        p += __shfl_xor(p, 2, 64);
        pc = p;
    }

    int s = row_start[n], e = row_start[n + 1];

    float cl = 0.f;
    float ca[16] = {};

    // process one gathered row (two us8) into (cl, ca); conversion on the fly
    auto proc = [&](const us8 ra, const us8 rb) {
        float p = 0.f;
#pragma unroll
        for (int j = 0; j < 8; j++) {
            float qa = bf2f(ra[j]) + hdf[j];
            p += fmaxf(qa, SLOPE * qa) * at[j];
            float qb = bf2f(rb[j]) + hdf[8 + j];
            p += fmaxf(qb, SLOPE * qb) * at[8 + j];
        }
        p += __shfl_xor(p, 1, 64);
        p += __shfl_xor(p, 2, 64);
        float wk = __expf(p - pc);
        cl += wk;
#pragma unroll
        for (int j = 0; j < 8; j++) {
            ca[j]     += wk * bf2f(ra[j]);
            ca[8 + j] += wk * bf2f(rb[j]);
        }
    };

    const us8 zz = {0, 0, 0, 0, 0, 0, 0, 0};
    auto loadA = [&](int sn) -> us8 {
        if (vA) return *(const us8*)(hs + (unsigned)(sn * 256 + f0));
        return zz;
    };
    auto loadB = [&](int sn) -> us8 {
        if (vB) return *(const us8*)(hs + (unsigned)(sn * 256 + f0 + 8));
        return zz;
    };

    int i = s;
    if (i + 4 <= e) {
        int a0 = src_sorted[i], a1 = src_sorted[i + 1];
        us8 c0a = loadA(a0), c0b = loadB(a0), c1a = loadA(a1), c1b = loadB(a1);
        int b0 = src_sorted[i + 2], b1 = src_sorted[i + 3];

        for (; i + 4 <= e; i += 2) {
            // issue next pair's gathers before current pair's VALU
            us8 n0a = loadA(b0), n0b = loadB(b0), n1a = loadA(b1), n1b = loadB(b1);
            // prefetch indices one stage further ahead
            if (i + 6 <= e) { b0 = src_sorted[i + 4]; b1 = src_sorted[i + 5]; }
            proc(c0a, c0b); proc(c1a, c1b);
            c0a = n0a; c0b = n0b; c1a = n1a; c1b = n1b;
        }
        // drain current pair
        proc(c0a, c0b); proc(c1a, c1b);
        i += 2;
    }
    // remainder (< 4 edges total, or <= 1 tail after pipeline)
    for (; i + 2 <= e; i += 2) {
        int a0 = src_sorted[i], a1 = src_sorted[i + 1];
        us8 r0a = loadA(a0), r0b = loadB(a0), r1a = loadA(a1), r1b = loadB(a1);
        proc(r0a, r0b); proc(r1a, r1b);
    }
    if (i < e) {
        int a0 = src_sorted[i];
        us8 r0a = loadA(a0), r0b = loadB(a0);
        proc(r0a, r0b);
    }

    float v[16] = {};
    if (e > s) {
        float inv = 1.f / cl;
#pragma unroll
        for (int j = 0; j < 16; j++)
            v[j] = ca[j] * inv;
    }

    if (FINAL) {
        // head-sum: lanes ql, ql^4, ql^8, ql^12 hold the same d-range across heads
#pragma unroll
        for (int j = 0; j < 16; j++) {
            v[j] += __shfl_xor(v[j], 4, 64);
            v[j] += __shfl_xor(v[j], 8, 64);
        }
        if (h == 0) {
#pragma unroll
            for (int jj = 0; jj < 16; jj += 4) {
                if (dp + jj < DVALID) {   // DVALID % 4 == 0 -> whole float4 valid
                    float* op = out_final + (unsigned)(n * DVALID + dp + jj);
                    float4 cur = *(float4*)op;
                    cur.x += 0.25f * v[jj];
                    cur.y += 0.25f * v[jj + 1];
                    cur.z += 0.25f * v[jj + 2];
                    cur.w += 0.25f * v[jj + 3];
                    *(float4*)op = cur;
                }
            }
        }
    } else {
        unsigned oi = (unsigned)(n * 256 + f0);
        if (RES_INPLACE) {
            us8 pa = *(const us8*)(P + oi);
            us8 pb = *(const us8*)(P + oi + 8);
#pragma unroll
            for (int j = 0; j < 8; j++) {
                v[j] += bf2f(pa[j]);
                v[8 + j] += bf2f(pb[j]);
            }
        }
        us8 oa, ob;
#pragma unroll
        for (int j = 0; j < 8; j++) {
            oa[j] = f2bf(v[j]);
            ob[j] = f2bf(v[8 + j]);
        }
        *(us8*)(P + oi) = oa;
        *(us8*)(P + oi + 8) = ob;
    }
}

// ---------------- launch ----------------

extern "C" void kernel_launch(void* const* d_in, const int* in_sizes, int n_in,
                              void* d_out, int out_size, void* d_ws, size_t ws_size,
                              hipStream_t stream) {
    const float* x0    = (const float*)d_in[0];
    const int*   src   = (const int*)d_in[1];
    const int*   dst   = (const int*)d_in[2];
    const float* w_src0 = (const float*)d_in[3];  const float* b_src0 = (const float*)d_in[4];
    const float* w_dst0 = (const float*)d_in[5];  const float* b_dst0 = (const float*)d_in[6];
    const float* attn0  = (const float*)d_in[7];
    const float* w_res0 = (const float*)d_in[8];  const float* b_res0 = (const float*)d_in[9];
    const float* w_src1 = (const float*)d_in[10]; const float* b_src1 = (const float*)d_in[11];
    const float* w_dst1 = (const float*)d_in[12]; const float* b_dst1 = (const float*)d_in[13];
    const float* attn1  = (const float*)d_in[14];
    const float* w_src2 = (const float*)d_in[15]; const float* b_src2 = (const float*)d_in[16];
    const float* w_dst2 = (const float*)d_in[17]; const float* b_dst2 = (const float*)d_in[18];
    const float* attn2  = (const float*)d_in[19];
    const float* w_res2 = (const float*)d_in[20]; const float* b_res2 = (const float*)d_in[21];

    const int N = in_sizes[0] / 128;   // 50000
    const int E = in_sizes[1];         // 400000
    float* out = (float*)d_out;
    (void)n_in; (void)out_size; (void)ws_size;

    // ---- workspace (~80 MB) ----
    char* ws = (char*)d_ws;
    size_t off = 0;
    auto alloc = [&](size_t bytes) {
        void* q = ws + off;
        off = (off + bytes + 255) & ~(size_t)255;
        return q;
    };
    int* deg        = (int*)alloc((size_t)2 * N * 4);
    int* fill       = deg + N;
    int* bcnt       = (int*)alloc(256 * 4);     // 128 bucket counts + 128 fill
    int* bfill      = bcnt + 128;
    int* perm       = (int*)alloc((size_t)N * 4);
    int* row_start  = (int*)alloc((size_t)(N + 1) * 4);
    int* chunk_sums = (int*)alloc(256 * 4);
    int* src_sorted = (int*)alloc((size_t)E * 4);
    bf16_t* t_src0 = (bf16_t*)alloc(256 * 128 * 2);
    bf16_t* t_dst0 = (bf16_t*)alloc(256 * 128 * 2);
    bf16_t* t_res0 = (bf16_t*)alloc(256 * 128 * 2);
    bf16_t* t_src1 = (bf16_t*)alloc(256 * 256 * 2);
    bf16_t* t_dst1 = (bf16_t*)alloc(256 * 256 * 2);
    bf16_t* t_src2 = (bf16_t*)alloc(192 * 256 * 2);
    bf16_t* t_dst2 = (bf16_t*)alloc(192 * 256 * 2);
    bf16_t* t_eff  = (bf16_t*)alloc(64 * 256 * 2);
    float*  b_eff  = (float*)alloc(64 * 4);
    const size_t elems = (size_t)N * 256;
    bf16_t* P  = (bf16_t*)alloc(elems * 2);
    bf16_t* HS = (bf16_t*)alloc(elems * 2);
    bf16_t* HD = (bf16_t*)alloc(elems * 2);

    // ---- CSR build + degree sort + weight conversion ----
    hipMemsetAsync(deg, 0, (size_t)2 * N * 4, stream);
    hipMemsetAsync(bcnt, 0, 256 * 4, stream);
    int eblocks = (E + 255) / 256;     // 1563
    int nchunks = (N + 1023) / 1024;   // 49 (<= 64 required by scan_write)
    hipLaunchKernelGGL(hist_and_convert, dim3(eblocks + 1344), dim3(256), 0, stream,
                       dst, E, eblocks, deg,
                       w_src0, w_dst0, w_res0, w_src1, w_dst1, w_src2, w_dst2, w_res2, b_res2,
                       t_src0, t_dst0, t_res0, t_src1, t_dst1, t_src2, t_dst2, t_eff, b_eff);
    hipLaunchKernelGGL(deg_chunk_sum, dim3(nchunks), dim3(256), 0, stream, deg, N, chunk_sums, bcnt);
    hipLaunchKernelGGL(scan_write, dim3(nchunks), dim3(256), 0, stream, deg, N, chunk_sums,
                       row_start, E, bcnt, bfill, perm);

    dim3 blk(256);
    int mtiles = (N + 63) / 64;        // 782
    int ab = (N + 15) / 16;            // 3125 (quarter-wave-per-node agg)

    // ---- Layer 0: fused hs|hd|res GEMM from x0, OVERLAPPED with edge scatter ----
    hipLaunchKernelGGL((gemm_lds<float, 3, 128, 256, false, false, true>),
                       dim3(mtiles + eblocks), blk, 0, stream,
                       x0, t_src0, t_dst0, t_res0, b_src0, b_dst0, b_res0,
                       HS, HD, P,
                       (const bf16_t*)nullptr, (const float*)nullptr, (float*)nullptr,
                       N, 256,
                       dst, src, E, row_start, fill, src_sorted, mtiles);
    hipLaunchKernelGGL((gat_agg_quarter<64, false, true>), dim3(ab), blk, 0, stream,
                       HS, HD, attn0, row_start, src_sorted, perm, P, (float*)nullptr, N);

    // ---- Layer 1: fused hs|hd from P; identity residual in-place ----
    hipLaunchKernelGGL((gemm_lds<bf16_t, 2, 256, 256, false, false, false>), dim3(mtiles), blk, 0, stream,
                       P, t_src1, t_dst1, (const bf16_t*)nullptr, b_src1, b_dst1, (const float*)nullptr,
                       HS, HD, (bf16_t*)nullptr,
                       (const bf16_t*)nullptr, (const float*)nullptr, (float*)nullptr,
                       N, 256,
                       (const int*)nullptr, (const int*)nullptr, 0,
                       (const int*)nullptr, (int*)nullptr, (int*)nullptr, 0);
    hipLaunchKernelGGL((gat_agg_quarter<64, false, true>), dim3(ab), blk, 0, stream,
                       HS, HD, attn1, row_start, src_sorted, perm, P, (float*)nullptr, N);

    // ---- Layer 2: fused hs|hd (SPLIT40) + eff residual (f32 -> out); FINAL agg accumulates ----
    hipLaunchKernelGGL((gemm_lds<bf16_t, 2, 256, 192, true, true, false>), dim3(mtiles), blk, 0, stream,
                       P, t_src2, t_dst2, (const bf16_t*)nullptr, b_src2, b_dst2, (const float*)nullptr,
                       HS, HD, (bf16_t*)nullptr,
                       t_eff, b_eff, out,
                       N, 160,
                       (const int*)nullptr, (const int*)nullptr, 0,
                       (const int*)nullptr, (int*)nullptr, (int*)nullptr, 0);
    hipLaunchKernelGGL((gat_agg_quarter<40, true, false>), dim3(ab), blk, 0, stream,
                       HS, HD, attn2, row_start, src_sorted, perm, (bf16_t*)nullptr, out, N);
}

// Round 21
// 399.147 us; speedup vs baseline: 1.4960x; 1.0046x over previous
//
#include <hip/hip_runtime.h>
#include <hip/hip_bf16.h>
#include <math.h>

// N=50000, E=400000, F_IN=128, HID=64, OUT=40, H=4
#define SLOPE 0.2f

typedef unsigned short bf16_t;
typedef short bh8 __attribute__((ext_vector_type(8)));
typedef unsigned short us8 __attribute__((ext_vector_type(8)));
typedef float f32x4 __attribute__((ext_vector_type(4)));

__device__ __forceinline__ float bf2f(bf16_t x) {
    return __uint_as_float((unsigned)x << 16);
}
__device__ __forceinline__ bf16_t f2bf(float v) {
    unsigned u = __float_as_uint(v);
    return (bf16_t)((u + 0x7FFFu + ((u >> 16) & 1u)) >> 16);  // RNE
}
__device__ __forceinline__ ushort2 pk_f2bf(float a, float b) {
    __hip_bfloat162 h2 = __float22bfloat162_rn(float2{a, b});  // v_cvt_pk_bf16_f32
    union { __hip_bfloat162 h; ushort2 u; } u;
    u.h = h2;
    return u.u;
}

// ---------------- fused histogram + weight conversion (R15/R16-verified) ----------------

__global__ void hist_and_convert(
    const int* __restrict__ dst, int E, int eblocks, int* __restrict__ deg,
    const float* __restrict__ w0, const float* __restrict__ w1, const float* __restrict__ w2,
    const float* __restrict__ w3, const float* __restrict__ w4,
    const float* __restrict__ w5, const float* __restrict__ w6,
    const float* __restrict__ wr2, const float* __restrict__ br2,
    bf16_t* __restrict__ t0, bf16_t* __restrict__ t1, bf16_t* __restrict__ t2,
    bf16_t* __restrict__ t3, bf16_t* __restrict__ t4,
    bf16_t* __restrict__ t5, bf16_t* __restrict__ t6,
    bf16_t* __restrict__ teff, float* __restrict__ b_eff)
{
    int t = threadIdx.x;
    if ((int)blockIdx.x < eblocks) {
        int e = blockIdx.x * 256 + t;
        if (e < E) atomicAdd(&deg[dst[e]], 1);
        return;
    }
    int b = blockIdx.x - eblocks;
    const float* W; bf16_t* T; int K, Nc, lb;
    if (b < 384) {
        int g = b / 128; lb = b - g * 128;
        W = g == 0 ? w0 : (g == 1 ? w1 : w2);
        T = g == 0 ? t0 : (g == 1 ? t1 : t2);
        K = 128; Nc = 256;
    } else if (b < 896) {
        int g = (b - 384) / 256; lb = (b - 384) - g * 256;
        W = g == 0 ? w3 : w4; T = g == 0 ? t3 : t4;
        K = 256; Nc = 256;
    } else if (b < 1280) {
        int g = (b - 896) / 192; lb = (b - 896) - g * 192;
        W = g == 0 ? w5 : w6; T = g == 0 ? t5 : t6;
        K = 256; Nc = 160;
    } else {
        lb = b - 1280;
        int idx = lb * 256 + t;          // 64*256 = 16384 elems
        int n = idx >> 8, k = idx & 255;
        float v = 0.f;
        if (n < 40)
            v = 0.25f * (wr2[(size_t)k * 160 + n] + wr2[(size_t)k * 160 + 40 + n] +
                         wr2[(size_t)k * 160 + 80 + n] + wr2[(size_t)k * 160 + 120 + n]);
        teff[idx] = f2bf(v);
        if (lb == 0 && t < 40)
            b_eff[t] = 0.25f * (br2[t] + br2[40 + t] + br2[80 + t] + br2[120 + t]);
        return;
    }
    int idx = lb * 256 + t;
    int n = idx / K, k = idx - n * K;
    float v = (n < Nc) ? W[(size_t)k * Nc + n] : 0.f;
    T[idx] = f2bf(v);
}

// ---------------- CSR scan + degree-bucket sort ----------------
// deg_chunk_sum additionally builds a 128-bucket degree histogram (LDS-staged).

__global__ void deg_chunk_sum(const int* __restrict__ deg, int n,
                              int* __restrict__ chunk_sums, int* __restrict__ bcnt) {
    __shared__ int sm[256];
    __shared__ int hl[128];
    int t = threadIdx.x;
    if (t < 128) hl[t] = 0;
    __syncthreads();
    int base = blockIdx.x * 1024;
    int s = 0;
    for (int i = t; i < 1024; i += 256) {
        int idx = base + i;
        if (idx < n) {
            int d = deg[idx];
            s += d;
            atomicAdd(&hl[d < 127 ? d : 127], 1);
        }
    }
    sm[t] = s;
    __syncthreads();
    for (int off = 128; off > 0; off >>= 1) {
        if (t < off) sm[t] += sm[t + off];
        __syncthreads();
    }
    if (t == 0) chunk_sums[blockIdx.x] = sm[0];
    if (t < 128 && hl[t]) atomicAdd(&bcnt[t], hl[t]);
}

// scan_write: row_start prefix (as before) + degree-sorted node permutation.
// Counting sort: per-block LDS rank within bucket, one global atomic per
// bucket per block, then scatter perm[sbase[b]+gbase[b]+rank] = node.
__global__ void scan_write(const int* __restrict__ deg, int n,
                           const int* __restrict__ chunk_sums,
                           int* __restrict__ row_start, int Etot,
                           const int* __restrict__ bcnt, int* __restrict__ bfill,
                           int* __restrict__ perm) {
    __shared__ int sm[256];
    __shared__ int s_pref;
    __shared__ int sbase[128];
    __shared__ int lcnt[128];
    __shared__ int gbase[128];
    int base = blockIdx.x * 1024;
    int t = threadIdx.x;

    if (t < 128) lcnt[t] = 0;

    // wave 0: sum chunk_sums[0..blockIdx.x) via wave-reduce
    if (t < 64) {
        int v = (t < (int)blockIdx.x) ? chunk_sums[t] : 0;
#pragma unroll
        for (int off = 32; off > 0; off >>= 1)
            v += __shfl_down(v, off, 64);
        if (t == 0) s_pref = v;
    }
    // thread 128: serial exclusive prefix of the 128-bucket histogram
    if (t == 128) {
        int run = 0;
        for (int i = 0; i < 128; i++) { sbase[i] = run; run += bcnt[i]; }
    }

    int vv[4];
    int tsum = 0;
#pragma unroll
    for (int j = 0; j < 4; j++) {
        int idx = base + t * 4 + j;
        vv[j] = (idx < n) ? deg[idx] : 0;
        tsum += vv[j];
    }
    sm[t] = tsum;
    __syncthreads();
    for (int off = 1; off < 256; off <<= 1) {
        int x = (t >= off) ? sm[t - off] : 0;
        __syncthreads();
        sm[t] += x;
        __syncthreads();
    }
    int excl = sm[t] - tsum + s_pref;
#pragma unroll
    for (int j = 0; j < 4; j++) {
        int idx = base + t * 4 + j;
        if (idx < n) row_start[idx] = excl;
        excl += vv[j];
    }
    if (blockIdx.x == 0 && t == 0) row_start[n] = Etot;

    // ---- degree-bucket scatter ----
    int rnk[4], bb[4];
#pragma unroll
    for (int j = 0; j < 4; j++) {
        int idx = base + t * 4 + j;
        if (idx < n) {
            bb[j] = vv[j] < 127 ? vv[j] : 127;
            rnk[j] = atomicAdd(&lcnt[bb[j]], 1);
        } else bb[j] = -1;
    }
    __syncthreads();
    if (t < 128 && lcnt[t]) gbase[t] = atomicAdd(&bfill[t], lcnt[t]);
    __syncthreads();
#pragma unroll
    for (int j = 0; j < 4; j++) {
        int idx = base + t * 4 + j;
        if (bb[j] >= 0)
            perm[sbase[bb[j]] + gbase[bb[j]] + rnk[j]] = idx;
    }
}

// ---------------- single-A-stage multi-output MFMA GEMM (R14/R17 config) ----------------
// DO_SCATTER: blocks [mtiles, mtiles+eblocks) run the edge scatter (independent
// work overlapped with the layer-0 GEMM in one dispatch) and return early.

template <typename TA, int NOUT, int KTOT, int NPAD, bool SPLIT40, bool HAS_EFF, bool DO_SCATTER>
__global__ __launch_bounds__(256) void gemm_lds(
    const TA* __restrict__ A,
    const bf16_t* __restrict__ Wt0, const bf16_t* __restrict__ Wt1, const bf16_t* __restrict__ Wt2,
    const float* __restrict__ bias0, const float* __restrict__ bias1, const float* __restrict__ bias2,
    bf16_t* __restrict__ C0, bf16_t* __restrict__ C1, bf16_t* __restrict__ C2,
    const bf16_t* __restrict__ Wte, const float* __restrict__ biase, float* __restrict__ Ce,
    int M, int Nc,
    const int* __restrict__ e_dst, const int* __restrict__ e_src, int E,
    const int* __restrict__ row_start, int* __restrict__ fill,
    int* __restrict__ src_sorted, int mtiles)
{
    constexpr int LSTR = KTOT + 8;     // stage row stride
    constexpr int ESTR = 38;           // epilogue row stride
    constexpr int KC = KTOT / 32;
    __shared__ bf16_t As[64 * LSTR];
    __shared__ bf16_t Ep[4 * 64 * ESTR];

    int tid = threadIdx.x;

    if (DO_SCATTER && (int)blockIdx.x >= mtiles) {
        int e = (blockIdx.x - mtiles) * 256 + tid;
        if (e < E) {
            int d_ = e_dst[e];
            int pos = row_start[d_] + atomicAdd(&fill[d_], 1);
            src_sorted[pos] = e_src[e];
        }
        return;
    }

    int lane = tid & 63, w = tid >> 6;
    int lm = lane & 15, lq = lane >> 4;
    int m0 = blockIdx.x * 64;

    const bf16_t* Wts[3] = {Wt0, Wt1, Wt2};
    const float* biases[3] = {bias0, bias1, bias2};
    bf16_t* Cs[3] = {C0, C1, C2};

    // ---- stage A slab (64 rows x KTOT) once ----
    if (sizeof(TA) == 4) {            // KTOT == 128, f32 input
#pragma unroll
        for (int it = 0; it < 4; it++) {
            int idx = tid + it * 256;  // 1024 chunks of 8 floats
            int r = idx >> 4, c = idx & 15;
            int gm = m0 + r; if (gm >= M) gm = M - 1;
            const float* ap = (const float*)A + (size_t)gm * KTOT + c * 8;
            float4 lo = *(const float4*)ap;
            float4 hi = *(const float4*)(ap + 4);
            ushort2 p0 = pk_f2bf(lo.x, lo.y), p1 = pk_f2bf(lo.z, lo.w);
            ushort2 p2 = pk_f2bf(hi.x, hi.y), p3 = pk_f2bf(hi.z, hi.w);
            bh8 v = { (short)p0.x, (short)p0.y, (short)p1.x, (short)p1.y,
                      (short)p2.x, (short)p2.y, (short)p3.x, (short)p3.y };
            *(bh8*)(As + r * LSTR + c * 8) = v;
        }
    } else {                           // KTOT == 256, bf16 input
#pragma unroll
        for (int it = 0; it < 8; it++) {
            int idx = tid + it * 256;  // 2048 chunks of 8 bf16
            int r = idx >> 5, c = idx & 31;
            int gm = m0 + r; if (gm >= M) gm = M - 1;
            bh8 v = *(const bh8*)((const bf16_t*)A + (size_t)gm * KTOT + c * 8);
            *(bh8*)(As + r * LSTR + c * 8) = v;
        }
    }
    __syncthreads();   // the ONLY barrier

    bf16_t* ep = Ep + w * (64 * ESTR);
    constexpr int NCHUNK = (NPAD + 127) / 128;

#pragma unroll
    for (int chunk = 0; chunk < NCHUNK; chunk++) {
        int n0 = chunk * 128 + w * 32;
        if (n0 >= NPAD) continue;      // no barriers inside -> safe

        int boff[NOUT][2];
#pragma unroll
        for (int o = 0; o < NOUT; o++)
#pragma unroll
            for (int nt = 0; nt < 2; nt++)
                boff[o][nt] = (n0 + nt * 16 + lm) * KTOT + lq * 8;

        f32x4 acc[NOUT][4][2];
#pragma unroll
        for (int o = 0; o < NOUT; o++)
#pragma unroll
            for (int i = 0; i < 4; i++)
#pragma unroll
                for (int j = 0; j < 2; j++)
                    acc[o][i][j] = (f32x4){0.f, 0.f, 0.f, 0.f};

        bh8 bf_cur[NOUT][2], bf_nxt[NOUT][2];
#pragma unroll
        for (int o = 0; o < NOUT; o++)
#pragma unroll
            for (int nt = 0; nt < 2; nt++)
                bf_cur[o][nt] = *(const bh8*)(Wts[o] + boff[o][nt]);

#pragma unroll
        for (int kc = 0; kc < KC; kc++) {
            if (kc + 1 < KC) {
#pragma unroll
                for (int o = 0; o < NOUT; o++)
#pragma unroll
                    for (int nt = 0; nt < 2; nt++)
                        bf_nxt[o][nt] = *(const bh8*)(Wts[o] + boff[o][nt] + (kc + 1) * 32);
            }
            bh8 af[4];
#pragma unroll
            for (int mt = 0; mt < 4; mt++)
                af[mt] = *(const bh8*)(As + (mt * 16 + lm) * LSTR + kc * 32 + lq * 8);
#pragma unroll
            for (int o = 0; o < NOUT; o++)
#pragma unroll
                for (int mt = 0; mt < 4; mt++)
#pragma unroll
                    for (int nt = 0; nt < 2; nt++)
                        acc[o][mt][nt] = __builtin_amdgcn_mfma_f32_16x16x32_bf16(af[mt], bf_cur[o][nt], acc[o][mt][nt], 0, 0, 0);
            if (kc + 1 < KC) {
#pragma unroll
                for (int o = 0; o < NOUT; o++)
#pragma unroll
                    for (int nt = 0; nt < 2; nt++)
                        bf_cur[o][nt] = bf_nxt[o][nt];
            }
        }

        // ---- per-wave epilogue: private LDS tile -> full-line global stores ----
#pragma unroll
        for (int o = 0; o < NOUT; o++) {
#pragma unroll
            for (int nt = 0; nt < 2; nt++) {
                int gn = n0 + nt * 16 + lm;
                float bv = (gn < Nc) ? biases[o][gn] : 0.f;
#pragma unroll
                for (int mt = 0; mt < 4; mt++)
#pragma unroll
                    for (int r = 0; r < 4; r++)
                        ep[(mt * 16 + lq * 4 + r) * ESTR + nt * 16 + lm] = f2bf(acc[o][mt][nt][r] + bv);
            }
#pragma unroll
            for (int it = 0; it < 4; it++) {
                int row = it * 16 + (lane >> 2);
                int cc = (lane & 3) * 8;
                bh8 v = *(const bh8*)(ep + row * ESTR + cc);
                int gm = m0 + row;
                int cg = n0 + cc;
                if (gm < M && cg < Nc) {
                    size_t cb = SPLIT40 ? (size_t)(cg + 24 * (cg / 40)) : (size_t)cg;
                    size_t rs = SPLIT40 ? 256 : (size_t)Nc;
                    *(bh8*)(Cs[o] + (size_t)gm * rs + cb) = v;
                }
            }
        }
    }

    // ---- folded-residual pass (waves 0-1), reuses LDS A ----
    if (HAS_EFF && w < 2) {
        int beoff[2];
#pragma unroll
        for (int nt = 0; nt < 2; nt++)
            beoff[nt] = (w * 32 + nt * 16 + lm) * KTOT + lq * 8;
        f32x4 acc_e[4][2];
#pragma unroll
        for (int i = 0; i < 4; i++)
#pragma unroll
            for (int j = 0; j < 2; j++)
                acc_e[i][j] = (f32x4){0.f, 0.f, 0.f, 0.f};
#pragma unroll
        for (int kc = 0; kc < KC; kc++) {
            bh8 af[4];
#pragma unroll
            for (int mt = 0; mt < 4; mt++)
                af[mt] = *(const bh8*)(As + (mt * 16 + lm) * LSTR + kc * 32 + lq * 8);
            bh8 be[2];
#pragma unroll
            for (int nt = 0; nt < 2; nt++)
                be[nt] = *(const bh8*)(Wte + beoff[nt] + kc * 32);
#pragma unroll
            for (int mt = 0; mt < 4; mt++)
#pragma unroll
                for (int nt = 0; nt < 2; nt++)
                    acc_e[mt][nt] = __builtin_amdgcn_mfma_f32_16x16x32_bf16(af[mt], be[nt], acc_e[mt][nt], 0, 0, 0);
        }
#pragma unroll
        for (int nt = 0; nt < 2; nt++) {
            int gn = w * 32 + nt * 16 + lm;
            if (gn >= 40) continue;
            float bv = biase[gn];
#pragma unroll
            for (int mt = 0; mt < 4; mt++)
#pragma unroll
                for (int r = 0; r < 4; r++) {
                    int gm = m0 + mt * 16 + lq * 4 + r;
                    if (gm < M) Ce[(size_t)gm * 40 + gn] = acc_e[mt][nt][r] + bv;
                }
        }
    }
}

// ---------------- GATv2 aggregation: QUARTER-WAVE per node, 2-edge pipeline ----------------
// R17 config (401.8us verified): plain __launch_bounds__(256) (R16 lesson:
// the ",4" hint targets 64 VGPR and force-spills), LPT order, 2-edge
// prefetch, on-the-fly bf16 conversion, index prefetch.
// R18/R20: DVALID-aware gather skip (measured ~neutral: agg is latency-bound,
// kept since it's free and removes reliance on pad-data finiteness).

__device__ __forceinline__ void us8_to_f(const us8 v, float* h) {
#pragma unroll
    for (int j = 0; j < 8; j++) h[j] = bf2f(v[j]);
}

template <int DVALID, bool FINAL, bool RES_INPLACE>
__global__ __launch_bounds__(256) void gat_agg_quarter(
    const bf16_t* __restrict__ hs, const bf16_t* __restrict__ hd,
    const float* __restrict__ attn,
    const int* __restrict__ row_start, const int* __restrict__ src_sorted,
    const int* __restrict__ perm,
    bf16_t* __restrict__ P, float* __restrict__ out_final, int N)
{
    int w = threadIdx.x >> 6, lane = threadIdx.x & 63;
    int q = lane >> 4, ql = lane & 15;
    int gq = blockIdx.x * 16 + w * 4 + q;
    if (gq >= N) return;
    int n = perm[(N - 1) - gq];   // descending degree: LPT scheduling
    int f0 = ql * 16;         // padded feature base
    int h = ql >> 2;          // head
    int dp = (ql & 3) * 16;   // d within head (padded)

    const bool vA = (dp < DVALID);       // first 8 dims of slice valid?
    const bool vB = (dp + 8 < DVALID);   // second 8 dims valid?

    float at[16], hdf[16];
#pragma unroll
    for (int j = 0; j < 16; j++)
        at[j] = (dp + j < DVALID) ? attn[h * DVALID + dp + j] : 0.f;
    {
        us8 z = {0, 0, 0, 0, 0, 0, 0, 0};
        us8 a = z, b = z;
        if (vA) a = *(const us8*)(hd + (unsigned)(n * 256 + f0));
        if (vB) b = *(const us8*)(hd + (unsigned)(n * 256 + f0 + 8));
        us8_to_f(a, hdf); us8_to_f(b, hdf + 8);
    }

    // per-node proxy center: logit at hs=0 (keeps exp args small; logits bounded)
    float pc;
    {
        float p = 0.f;
#pragma unroll
        for (int j = 0; j < 16; j++) {
            float qq = hdf[j];
            p += fmaxf(qq, SLOPE * qq) * at[j];
        }
        p += __shfl_xor(p, 1, 64);
        p += __shfl_xor(p, 2, 64);
        pc = p;
    }

    int s = row_start[n], e = row_start[n + 1];

    float cl = 0.f;
    float ca[16] = {};

    // process one gathered row (two us8) into (cl, ca); conversion on the fly
    auto proc = [&](const us8 ra, const us8 rb) {
        float p = 0.f;
#pragma unroll
        for (int j = 0; j < 8; j++) {
            float qa = bf2f(ra[j]) + hdf[j];
            p += fmaxf(qa, SLOPE * qa) * at[j];
            float qb = bf2f(rb[j]) + hdf[8 + j];
            p += fmaxf(qb, SLOPE * qb) * at[8 + j];
        }
        p += __shfl_xor(p, 1, 64);
        p += __shfl_xor(p, 2, 64);
        float wk = __expf(p - pc);
        cl += wk;
#pragma unroll
        for (int j = 0; j < 8; j++) {
            ca[j]     += wk * bf2f(ra[j]);
            ca[8 + j] += wk * bf2f(rb[j]);
        }
    };

    const us8 zz = {0, 0, 0, 0, 0, 0, 0, 0};
    auto loadA = [&](int sn) -> us8 {
        if (vA) return *(const us8*)(hs + (unsigned)(sn * 256 + f0));
        return zz;
    };
    auto loadB = [&](int sn) -> us8 {
        if (vB) return *(const us8*)(hs + (unsigned)(sn * 256 + f0 + 8));
        return zz;
    };

    int i = s;
    if (i + 4 <= e) {
        int a0 = src_sorted[i], a1 = src_sorted[i + 1];
        us8 c0a = loadA(a0), c0b = loadB(a0), c1a = loadA(a1), c1b = loadB(a1);
        int b0 = src_sorted[i + 2], b1 = src_sorted[i + 3];

        for (; i + 4 <= e; i += 2) {
            // issue next pair's gathers before current pair's VALU
            us8 n0a = loadA(b0), n0b = loadB(b0), n1a = loadA(b1), n1b = loadB(b1);
            // prefetch indices one stage further ahead
            if (i + 6 <= e) { b0 = src_sorted[i + 4]; b1 = src_sorted[i + 5]; }
            proc(c0a, c0b); proc(c1a, c1b);
            c0a = n0a; c0b = n0b; c1a = n1a; c1b = n1b;
        }
        // drain current pair
        proc(c0a, c0b); proc(c1a, c1b);
        i += 2;
    }
    // remainder (< 4 edges total, or <= 1 tail after pipeline)
    for (; i + 2 <= e; i += 2) {
        int a0 = src_sorted[i], a1 = src_sorted[i + 1];
        us8 r0a = loadA(a0), r0b = loadB(a0), r1a = loadA(a1), r1b = loadB(a1);
        proc(r0a, r0b); proc(r1a, r1b);
    }
    if (i < e) {
        int a0 = src_sorted[i];
        us8 r0a = loadA(a0), r0b = loadB(a0);
        proc(r0a, r0b);
    }

    float v[16] = {};
    if (e > s) {
        float inv = 1.f / cl;
#pragma unroll
        for (int j = 0; j < 16; j++)
            v[j] = ca[j] * inv;
    }

    if (FINAL) {
        // head-sum: lanes ql, ql^4, ql^8, ql^12 hold the same d-range across heads
#pragma unroll
        for (int j = 0; j < 16; j++) {
            v[j] += __shfl_xor(v[j], 4, 64);
            v[j] += __shfl_xor(v[j], 8, 64);
        }
        if (h == 0) {
#pragma unroll
            for (int jj = 0; jj < 16; jj += 4) {
                if (dp + jj < DVALID) {   // DVALID % 4 == 0 -> whole float4 valid
                    float* op = out_final + (unsigned)(n * DVALID + dp + jj);
                    float4 cur = *(float4*)op;
                    cur.x += 0.25f * v[jj];
                    cur.y += 0.25f * v[jj + 1];
                    cur.z += 0.25f * v[jj + 2];
                    cur.w += 0.25f * v[jj + 3];
                    *(float4*)op = cur;
                }
            }
        }
    } else {
        unsigned oi = (unsigned)(n * 256 + f0);
        if (RES_INPLACE) {
            us8 pa = *(const us8*)(P + oi);
            us8 pb = *(const us8*)(P + oi + 8);
#pragma unroll
            for (int j = 0; j < 8; j++) {
                v[j] += bf2f(pa[j]);
                v[8 + j] += bf2f(pb[j]);
            }
        }
        us8 oa, ob;
#pragma unroll
        for (int j = 0; j < 8; j++) {
            oa[j] = f2bf(v[j]);
            ob[j] = f2bf(v[8 + j]);
        }
        *(us8*)(P + oi) = oa;
        *(us8*)(P + oi + 8) = ob;
    }
}

// ---------------- launch ----------------

extern "C" void kernel_launch(void* const* d_in, const int* in_sizes, int n_in,
                              void* d_out, int out_size, void* d_ws, size_t ws_size,
                              hipStream_t stream) {
    const float* x0    = (const float*)d_in[0];
    const int*   src   = (const int*)d_in[1];
    const int*   dst   = (const int*)d_in[2];
    const float* w_src0 = (const float*)d_in[3];  const float* b_src0 = (const float*)d_in[4];
    const float* w_dst0 = (const float*)d_in[5];  const float* b_dst0 = (const float*)d_in[6];
    const float* attn0  = (const float*)d_in[7];
    const float* w_res0 = (const float*)d_in[8];  const float* b_res0 = (const float*)d_in[9];
    const float* w_src1 = (const float*)d_in[10]; const float* b_src1 = (const float*)d_in[11];
    const float* w_dst1 = (const float*)d_in[12]; const float* b_dst1 = (const float*)d_in[13];
    const float* attn1  = (const float*)d_in[14];
    const float* w_src2 = (const float*)d_in[15]; const float* b_src2 = (const float*)d_in[16];
    const float* w_dst2 = (const float*)d_in[17]; const float* b_dst2 = (const float*)d_in[18];
    const float* attn2  = (const float*)d_in[19];
    const float* w_res2 = (const float*)d_in[20]; const float* b_res2 = (const float*)d_in[21];

    const int N = in_sizes[0] / 128;   // 50000
    const int E = in_sizes[1];         // 400000
    float* out = (float*)d_out;
    (void)n_in; (void)out_size; (void)ws_size;

    // ---- workspace (~80 MB) ----
    char* ws = (char*)d_ws;
    size_t off = 0;
    auto alloc = [&](size_t bytes) {
        void* q = ws + off;
        off = (off + bytes + 255) & ~(size_t)255;
        return q;
    };
    // deg/fill and bcnt/bfill allocated contiguously -> ONE memset clears all
    int* deg        = (int*)alloc((size_t)2 * N * 4);
    int* fill       = deg + N;
    int* bcnt       = (int*)alloc(256 * 4);     // 128 bucket counts + 128 fill
    int* bfill      = bcnt + 128;
    size_t zero_bytes = (size_t)((char*)bcnt - (char*)deg) + 256 * 4;  // covers deg,fill,pad,bcnt,bfill
    int* perm       = (int*)alloc((size_t)N * 4);
    int* row_start  = (int*)alloc((size_t)(N + 1) * 4);
    int* chunk_sums = (int*)alloc(256 * 4);
    int* src_sorted = (int*)alloc((size_t)E * 4);
    bf16_t* t_src0 = (bf16_t*)alloc(256 * 128 * 2);
    bf16_t* t_dst0 = (bf16_t*)alloc(256 * 128 * 2);
    bf16_t* t_res0 = (bf16_t*)alloc(256 * 128 * 2);
    bf16_t* t_src1 = (bf16_t*)alloc(256 * 256 * 2);
    bf16_t* t_dst1 = (bf16_t*)alloc(256 * 256 * 2);
    bf16_t* t_src2 = (bf16_t*)alloc(192 * 256 * 2);
    bf16_t* t_dst2 = (bf16_t*)alloc(192 * 256 * 2);
    bf16_t* t_eff  = (bf16_t*)alloc(64 * 256 * 2);
    float*  b_eff  = (float*)alloc(64 * 4);
    const size_t elems = (size_t)N * 256;
    bf16_t* P  = (bf16_t*)alloc(elems * 2);
    bf16_t* HS = (bf16_t*)alloc(elems * 2);
    bf16_t* HD = (bf16_t*)alloc(elems * 2);

    // ---- CSR build + degree sort + weight conversion ----
    hipMemsetAsync(deg, 0, zero_bytes, stream);   // deg + fill + bcnt + bfill in one shot
    int eblocks = (E + 255) / 256;     // 1563
    int nchunks = (N + 1023) / 1024;   // 49 (<= 64 required by scan_write)
    hipLaunchKernelGGL(hist_and_convert, dim3(eblocks + 1344), dim3(256), 0, stream,
                       dst, E, eblocks, deg,
                       w_src0, w_dst0, w_res0, w_src1, w_dst1, w_src2, w_dst2, w_res2, b_res2,
                       t_src0, t_dst0, t_res0, t_src1, t_dst1, t_src2, t_dst2, t_eff, b_eff);
    hipLaunchKernelGGL(deg_chunk_sum, dim3(nchunks), dim3(256), 0, stream, deg, N, chunk_sums, bcnt);
    hipLaunchKernelGGL(scan_write, dim3(nchunks), dim3(256), 0, stream, deg, N, chunk_sums,
                       row_start, E, bcnt, bfill, perm);

    dim3 blk(256);
    int mtiles = (N + 63) / 64;        // 782
    int ab = (N + 15) / 16;            // 3125 (quarter-wave-per-node agg)

    // ---- Layer 0: fused hs|hd|res GEMM from x0, OVERLAPPED with edge scatter ----
    hipLaunchKernelGGL((gemm_lds<float, 3, 128, 256, false, false, true>),
                       dim3(mtiles + eblocks), blk, 0, stream,
                       x0, t_src0, t_dst0, t_res0, b_src0, b_dst0, b_res0,
                       HS, HD, P,
                       (const bf16_t*)nullptr, (const float*)nullptr, (float*)nullptr,
                       N, 256,
                       dst, src, E, row_start, fill, src_sorted, mtiles);
    hipLaunchKernelGGL((gat_agg_quarter<64, false, true>), dim3(ab), blk, 0, stream,
                       HS, HD, attn0, row_start, src_sorted, perm, P, (float*)nullptr, N);

    // ---- Layer 1: fused hs|hd from P; identity residual in-place ----
    hipLaunchKernelGGL((gemm_lds<bf16_t, 2, 256, 256, false, false, false>), dim3(mtiles), blk, 0, stream,
                       P, t_src1, t_dst1, (const bf16_t*)nullptr, b_src1, b_dst1, (const float*)nullptr,
                       HS, HD, (bf16_t*)nullptr,
                       (const bf16_t*)nullptr, (const float*)nullptr, (float*)nullptr,
                       N, 256,
                       (const int*)nullptr, (const int*)nullptr, 0,
                       (const int*)nullptr, (int*)nullptr, (int*)nullptr, 0);
    hipLaunchKernelGGL((gat_agg_quarter<64, false, true>), dim3(ab), blk, 0, stream,
                       HS, HD, attn1, row_start, src_sorted, perm, P, (float*)nullptr, N);

    // ---- Layer 2: fused hs|hd (SPLIT40) + eff residual (f32 -> out); FINAL agg accumulates ----
    hipLaunchKernelGGL((gemm_lds<bf16_t, 2, 256, 192, true, true, false>), dim3(mtiles), blk, 0, stream,
                       P, t_src2, t_dst2, (const bf16_t*)nullptr, b_src2, b_dst2, (const float*)nullptr,
                       HS, HD, (bf16_t*)nullptr,
                       t_eff, b_eff, out,
                       N, 160,
                       (const int*)nullptr, (const int*)nullptr, 0,
                       (const int*)nullptr, (int*)nullptr, (int*)nullptr, 0);
    hipLaunchKernelGGL((gat_agg_quarter<40, true, false>), dim3(ab), blk, 0, stream,
                       HS, HD, attn2, row_start, src_sorted, perm, (bf16_t*)nullptr, out, N);
}